// Round 2
// baseline (6343.055 us; speedup 1.0000x reference)
//
#include <hip/hip_runtime.h>
#include <hip/hip_bf16.h>
#include <math.h>

#define NN   50000
#define EE   400000
#define NINP 256
#define HH   4
#define DD   32
#define HIDD 128
#define TNN  4
#define TEE  6
#define LLL  2
#define NOUTT 16

__device__ __forceinline__ float bf_lo(unsigned u) { return __uint_as_float(u << 16); }
__device__ __forceinline__ float bf_hi(unsigned u) { return __uint_as_float(u & 0xFFFF0000u); }
__device__ __forceinline__ unsigned short f2bf(float f) {
    unsigned u = __float_as_uint(f);
    u += 0x7FFFu + ((u >> 16) & 1u);
    return (unsigned short)(u >> 16);
}

// ---------------- workspace init (replaces hipMemsetAsync) ----------------
__global__ void k_init(int* __restrict__ deg, int* __restrict__ cur, int* __restrict__ ncnt,
                       int* __restrict__ ncur, int* __restrict__ nperm) {
    int i = blockIdx.x * 256 + threadIdx.x;
    if (i < NN) { deg[i] = 0; cur[i] = 0; }
    if (i < 16) { ncnt[i] = 0; ncur[i] = 0; }
    if (i < NN + 512) nperm[i] = -1;
}

// ---------------- CSR / sort build ----------------
__global__ void k_count_edges(const int* __restrict__ dst, int* __restrict__ deg) {
    int e = blockIdx.x * 256 + threadIdx.x;
    if (e < EE) atomicAdd(&deg[dst[e]], 1);
}
__global__ void k_count_types(const int* __restrict__ ntype, int* __restrict__ ncnt) {
    int n = blockIdx.x * 256 + threadIdx.x;
    if (n < NN) atomicAdd(&ncnt[ntype[n]], 1);
}
__global__ void k_scan(const int* __restrict__ deg, int* __restrict__ offs,
                       const int* __restrict__ ncnt, int* __restrict__ meta) {
    __shared__ int s[1024];
    int tid = threadIdx.x;
    int carry = 0;
    if (tid == 0) offs[0] = 0;
    for (int base = 0; base < NN; base += 1024) {
        int i = base + tid;
        int v = (i < NN) ? deg[i] : 0;
        s[tid] = v;
        __syncthreads();
        for (int off = 1; off < 1024; off <<= 1) {
            int add = (tid >= off) ? s[tid - off] : 0;
            __syncthreads();
            s[tid] += add;
            __syncthreads();
        }
        if (i < NN) offs[i + 1] = carry + s[tid];
        carry += s[1023];
        __syncthreads();
    }
    if (tid == 0) {  // padded (to 64) row starts per node type
        int acc = 0;
        meta[0] = 0;
        for (int t = 0; t < TNN; t++) { acc += ((ncnt[t] + 63) >> 6) << 6; meta[t + 1] = acc; }
    }
}
__global__ void k_scatter_edges(const int* __restrict__ dst, const int* __restrict__ offs,
                                int* __restrict__ cur, int* __restrict__ eidx) {
    int e = blockIdx.x * 256 + threadIdx.x;
    if (e < EE) {
        int d = dst[e];
        int p = atomicAdd(&cur[d], 1);
        eidx[offs[d] + p] = e;
    }
}
__global__ void k_scatter_nodes(const int* __restrict__ ntype, const int* __restrict__ meta,
                                int* __restrict__ ncur, int* __restrict__ nperm) {
    int n = blockIdx.x * 256 + threadIdx.x;
    if (n < NN) {
        int t = ntype[n];
        int p = atomicAdd(&ncur[t], 1);
        nperm[meta[t] + p] = n;
    }
}

// ---------------- typed GEMM: Y[node] = X[node] @ W[type(node)] (+bias,gelu) ----------------
// BM=64, BN=128, BK=16, 256 threads, each thread 4 rows x 8 cols
template <int K, int EPI>
__global__ void k_typed_gemm(const float* __restrict__ X, const float* __restrict__ W,
                             const float* __restrict__ B, float* __restrict__ Y,
                             const int* __restrict__ nperm, const int* __restrict__ meta) {
    __shared__ float As[16][64];
    __shared__ float Bs[16][128];
    int tile = blockIdx.x;
    int row0 = tile * 64;
    if (row0 >= meta[4]) return;
    int t = 0;
    while (t < 3 && row0 >= meta[t + 1]) t++;
    const float* Wt = W + (size_t)t * K * 128;
    int tid = threadIdx.x;
    int am = tid & 63;
    int ak4 = (tid >> 6) * 4;
    int anode = nperm[row0 + am];
    int tr = tid & 15;
    int tc = tid >> 4;
    float acc[4][8];
#pragma unroll
    for (int i = 0; i < 4; i++)
#pragma unroll
        for (int j = 0; j < 8; j++) acc[i][j] = 0.f;

    for (int k0 = 0; k0 < K; k0 += 16) {
        float4 av = make_float4(0.f, 0.f, 0.f, 0.f);
        if (anode >= 0) av = *(const float4*)(X + (size_t)anode * K + k0 + ak4);
        As[ak4 + 0][am] = av.x; As[ak4 + 1][am] = av.y;
        As[ak4 + 2][am] = av.z; As[ak4 + 3][am] = av.w;
#pragma unroll
        for (int it = 0; it < 2; it++) {
            int idx = tid + it * 256;
            int kb = idx >> 5;
            int nb = (idx & 31) * 4;
            *(float4*)(&Bs[kb][nb]) = *(const float4*)(Wt + (size_t)(k0 + kb) * 128 + nb);
        }
        __syncthreads();
#pragma unroll
        for (int kk = 0; kk < 16; kk++) {
            float4 a4 = *(const float4*)(&As[kk][tr * 4]);
            float4 b0 = *(const float4*)(&Bs[kk][tc * 4]);
            float4 b1 = *(const float4*)(&Bs[kk][64 + tc * 4]);
            float avv[4] = {a4.x, a4.y, a4.z, a4.w};
            float bvv[8] = {b0.x, b0.y, b0.z, b0.w, b1.x, b1.y, b1.z, b1.w};
#pragma unroll
            for (int i = 0; i < 4; i++)
#pragma unroll
                for (int j = 0; j < 8; j++) acc[i][j] += avv[i] * bvv[j];
        }
        __syncthreads();
    }
#pragma unroll
    for (int i = 0; i < 4; i++) {
        int node = nperm[row0 + tr * 4 + i];
        if (node < 0) continue;
        float4 o0 = make_float4(acc[i][0], acc[i][1], acc[i][2], acc[i][3]);
        float4 o1 = make_float4(acc[i][4], acc[i][5], acc[i][6], acc[i][7]);
        if (EPI == 1) {
            const float* bt = B + t * 128;
            float4 c0 = *(const float4*)(bt + tc * 4);
            float4 c1 = *(const float4*)(bt + 64 + tc * 4);
            o0.x += c0.x; o0.y += c0.y; o0.z += c0.z; o0.w += c0.w;
            o1.x += c1.x; o1.y += c1.y; o1.z += c1.z; o1.w += c1.w;
            const float is2 = 0.70710678118654752f;
            o0.x = 0.5f * o0.x * (1.f + erff(o0.x * is2));
            o0.y = 0.5f * o0.y * (1.f + erff(o0.y * is2));
            o0.z = 0.5f * o0.z * (1.f + erff(o0.z * is2));
            o0.w = 0.5f * o0.w * (1.f + erff(o0.w * is2));
            o1.x = 0.5f * o1.x * (1.f + erff(o1.x * is2));
            o1.y = 0.5f * o1.y * (1.f + erff(o1.y * is2));
            o1.z = 0.5f * o1.z * (1.f + erff(o1.z * is2));
            o1.w = 0.5f * o1.w * (1.f + erff(o1.w * is2));
        }
        *(float4*)(Y + (size_t)node * 128 + tc * 4) = o0;
        *(float4*)(Y + (size_t)node * 128 + 64 + tc * 4) = o1;
    }
}

// ---------------- q-hat / v-hat: per (h,t) 32x32 projection, bf16 out ----------------
// MODE 0: out[n,gy,d] = sum_o A[n,h*32+o] * W[gy][d][o]   (qhat: score = k . qhat)
// MODE 1: out[n,gy,o] = sum_d A[n,h*32+d] * W[gy][d][o]   (vhat: v @ Wm)
template <int MODE>
__global__ void k_hat(const float* __restrict__ A, const float* __restrict__ W,
                      unsigned short* __restrict__ O) {
    __shared__ float AsT[32][68];  // stride 68: keeps float4 reads 16B-aligned (65 faulted!)
    __shared__ float Ws[32][33];
    int gy = blockIdx.y;
    int h = gy / TEE;
    int n0 = blockIdx.x * 64;
    int tid = threadIdx.x;
    {
        int r = tid >> 3;
        int c4 = (tid & 7) * 4;
        float4 wv = *(const float4*)(W + (size_t)gy * 1024 + r * 32 + c4);
        Ws[r][c4] = wv.x; Ws[r][c4 + 1] = wv.y; Ws[r][c4 + 2] = wv.z; Ws[r][c4 + 3] = wv.w;
    }
#pragma unroll
    for (int it = 0; it < 2; it++) {
        int idx = tid + it * 256;
        int r = idx & 63;
        int j4 = (idx >> 6) * 4;
        int n = n0 + r;
        float4 av = make_float4(0.f, 0.f, 0.f, 0.f);
        if (n < NN) av = *(const float4*)(A + (size_t)n * 128 + h * 32 + j4);
        AsT[j4][r] = av.x; AsT[j4 + 1][r] = av.y; AsT[j4 + 2][r] = av.z; AsT[j4 + 3][r] = av.w;
    }
    __syncthreads();
    int c = tid & 31;
    int rowg = tid >> 5;
    float acc[8];
#pragma unroll
    for (int i = 0; i < 8; i++) acc[i] = 0.f;
#pragma unroll
    for (int j = 0; j < 32; j++) {
        float w = (MODE == 0) ? Ws[c][j] : Ws[j][c];
        float4 a0 = *(const float4*)(&AsT[j][rowg * 8]);
        float4 a1 = *(const float4*)(&AsT[j][rowg * 8 + 4]);
        acc[0] += a0.x * w; acc[1] += a0.y * w; acc[2] += a0.z * w; acc[3] += a0.w * w;
        acc[4] += a1.x * w; acc[5] += a1.y * w; acc[6] += a1.z * w; acc[7] += a1.w * w;
    }
#pragma unroll
    for (int i = 0; i < 8; i++) {
        int n = n0 + rowg * 8 + i;
        if (n < NN) O[(size_t)n * 768 + gy * 32 + c] = f2bf(acc[i]);
    }
}

// ---------------- fused edge pass: score + softmax(shift-free) + aggregate ----------------
// wave per dst node; lane = (h = lane>>4, pair i2 = (lane&15)*2)
__global__ void k_edge(const float* __restrict__ kbuf, const unsigned short* __restrict__ qhat,
                       const unsigned short* __restrict__ vhat, const float* __restrict__ pri,
                       const int* __restrict__ offs, const int* __restrict__ eidx,
                       const int* __restrict__ src, const int* __restrict__ etype,
                       float* __restrict__ agg) {
    int lane = threadIdx.x & 63;
    int wid = blockIdx.x * (blockDim.x >> 6) + (threadIdx.x >> 6);
    int nw = gridDim.x * (blockDim.x >> 6);
    int h = lane >> 4;
    int i2 = (lane & 15) * 2;
    const float rsD = 0.17677669529663687f;  // 1/sqrt(32)
    for (int n = wid; n < NN; n += nw) {
        int e0 = offs[n], e1 = offs[n + 1];
        float2 acc = make_float2(0.f, 0.f);
        float den = 0.f;
        const unsigned short* qrow = qhat + (size_t)n * 768;
        for (int j = e0; j < e1; j++) {
            int e = eidx[j];
            int s = src[e];
            int t = etype[e];
            float2 k2 = *(const float2*)(kbuf + (size_t)s * 128 + h * 32 + i2);
            unsigned qu = *(const unsigned*)(qrow + (h * TEE + t) * 32 + i2);
            unsigned vu = *(const unsigned*)(vhat + (size_t)s * 768 + (h * TEE + t) * 32 + i2);
            float part = k2.x * bf_lo(qu) + k2.y * bf_hi(qu);
            part += __shfl_xor(part, 1);
            part += __shfl_xor(part, 2);
            part += __shfl_xor(part, 4);
            part += __shfl_xor(part, 8);
            float ex = __expf(part * pri[h * TEE + t] * rsD);
            den += ex;
            acc.x += ex * bf_lo(vu);
            acc.y += ex * bf_hi(vu);
        }
        float r = (e1 > e0) ? (1.0f / den) : 0.f;
        *(float2*)(agg + (size_t)n * 128 + h * 32 + i2) = make_float2(acc.x * r, acc.y * r);
    }
}

// ---------------- skip-blend + LayerNorm (in-place into h) ----------------
__global__ void k_blend_ln(const float* __restrict__ ha, float* __restrict__ h,
                           const int* __restrict__ ntype, const float* __restrict__ skip,
                           const float* __restrict__ gamma, const float* __restrict__ beta) {
    int lane = threadIdx.x & 63;
    int w = threadIdx.x >> 6;
    int n = blockIdx.x * 4 + w;
    if (n >= NN) return;
    int off = lane * 2;
    int t = ntype[n];
    float alpha = 1.0f / (1.0f + __expf(-skip[t]));
    float2 a2 = *(const float2*)(ha + (size_t)n * 128 + off);
    float2 h2 = *(const float2*)(h + (size_t)n * 128 + off);
    float ox = a2.x * alpha + h2.x * (1.f - alpha);
    float oy = a2.y * alpha + h2.y * (1.f - alpha);
    float s = ox + oy;
#pragma unroll
    for (int m = 1; m < 64; m <<= 1) s += __shfl_xor(s, m);
    float mu = s * (1.0f / 128.0f);
    float dx = ox - mu, dy = oy - mu;
    float v = dx * dx + dy * dy;
#pragma unroll
    for (int m = 1; m < 64; m <<= 1) v += __shfl_xor(v, m);
    float rs = rsqrtf(v * (1.0f / 128.0f) + 1e-5f);
    float2 g2 = *(const float2*)(gamma + off);
    float2 b2 = *(const float2*)(beta + off);
    *(float2*)(h + (size_t)n * 128 + off) =
        make_float2(dx * rs * g2.x + b2.x, dy * rs * g2.y + b2.y);
}

// ---------------- output projection: out = h @ Wo + bo ----------------
__global__ void k_out(const float* __restrict__ h, const float* __restrict__ Wo,
                      const float* __restrict__ bo, float* __restrict__ out) {
    __shared__ float Ws[128 * 16];
    int tid = threadIdx.x;
#pragma unroll
    for (int it = 0; it < 2; it++) {
        int idx = (tid + it * 256) * 4;
        *(float4*)(&Ws[idx]) = *(const float4*)(Wo + idx);
    }
    __syncthreads();
    int nl = tid >> 4;
    int o = tid & 15;
    int n = blockIdx.x * 16 + nl;
    float acc = bo[o];
    const float* hr = h + (size_t)n * 128;
#pragma unroll
    for (int kk = 0; kk < 128; kk += 4) {
        float4 hv = *(const float4*)(hr + kk);
        acc += hv.x * Ws[kk * 16 + o] + hv.y * Ws[(kk + 1) * 16 + o] +
               hv.z * Ws[(kk + 2) * 16 + o] + hv.w * Ws[(kk + 3) * 16 + o];
    }
    out[(size_t)n * 16 + o] = acc;
}

extern "C" void kernel_launch(void* const* d_in, const int* in_sizes, int n_in,
                              void* d_out, int out_size, void* d_ws, size_t ws_size,
                              hipStream_t stream) {
    const float* x       = (const float*)d_in[0];
    const float* adapt_W = (const float*)d_in[1];
    const float* adapt_b = (const float*)d_in[2];
    const float* Wk      = (const float*)d_in[3];
    const float* Wq      = (const float*)d_in[4];
    const float* Wv      = (const float*)d_in[5];
    const float* pri     = (const float*)d_in[6];
    const float* Wa      = (const float*)d_in[7];
    const float* Wm      = (const float*)d_in[8];
    const float* Wla     = (const float*)d_in[9];
    const float* skip    = (const float*)d_in[10];
    const float* gamma   = (const float*)d_in[11];
    const float* beta    = (const float*)d_in[12];
    const float* out_W   = (const float*)d_in[13];
    const float* out_b   = (const float*)d_in[14];
    const int* ntype     = (const int*)d_in[15];
    const int* etype     = (const int*)d_in[16];
    const int* src       = (const int*)d_in[17];
    const int* dst       = (const int*)d_in[18];
    float* out = (float*)d_out;

    char* p = (char*)d_ws;
    auto al = [](size_t v) { return (v + 255) & ~(size_t)255; };
    size_t fsz = (size_t)NN * 128 * 4;
    float* h    = (float*)p; p += al(fsz);
    float* kbuf = (float*)p; p += al(fsz);
    float* qbuf = (float*)p; p += al(fsz);
    float* vbuf = (float*)p; p += al(fsz);
    unsigned short* qhat = (unsigned short*)p; p += al((size_t)NN * 768 * 2);
    unsigned short* vhat = (unsigned short*)p; p += al((size_t)NN * 768 * 2);
    int* deg   = (int*)p; p += al((size_t)NN * 4);
    int* offs  = (int*)p; p += al((size_t)(NN + 1) * 4);
    int* cur   = (int*)p; p += al((size_t)NN * 4);
    int* eidx  = (int*)p; p += al((size_t)EE * 4);
    int* nperm = (int*)p; p += al((size_t)(NN + 512) * 4);
    int* ncnt  = (int*)p; p += al(64);
    int* ncur  = (int*)p; p += al(64);
    int* meta  = (int*)p; p += al(64);
    float* agg = qbuf;  // qbuf dead after k_hat<0>
    float* ha  = vbuf;  // vbuf dead after k_hat<1>

    k_init<<<(NN + 512 + 255) / 256, 256, 0, stream>>>(deg, cur, ncnt, ncur, nperm);
    k_count_edges<<<(EE + 255) / 256, 256, 0, stream>>>(dst, deg);
    k_count_types<<<(NN + 255) / 256, 256, 0, stream>>>(ntype, ncnt);
    k_scan<<<1, 1024, 0, stream>>>(deg, offs, ncnt, meta);
    k_scatter_edges<<<(EE + 255) / 256, 256, 0, stream>>>(dst, offs, cur, eidx);
    k_scatter_nodes<<<(NN + 255) / 256, 256, 0, stream>>>(ntype, meta, ncur, nperm);

    const int TILES = NN / 64 + TNN + 1;  // padded tile upper bound
    const int HTILES = (NN + 63) / 64;

    k_typed_gemm<256, 1><<<TILES, 256, 0, stream>>>(x, adapt_W, adapt_b, h, nperm, meta);

    for (int l = 0; l < LLL; l++) {
        const float* Wkl = Wk + (size_t)l * TNN * HIDD * HIDD;
        const float* Wql = Wq + (size_t)l * TNN * HIDD * HIDD;
        const float* Wvl = Wv + (size_t)l * TNN * HIDD * HIDD;
        const float* Wll = Wla + (size_t)l * TNN * HIDD * HIDD;
        const float* Wal = Wa + (size_t)l * HH * TEE * DD * DD;
        const float* Wml = Wm + (size_t)l * HH * TEE * DD * DD;

        k_typed_gemm<128, 0><<<TILES, 256, 0, stream>>>(h, Wkl, nullptr, kbuf, nperm, meta);
        k_typed_gemm<128, 0><<<TILES, 256, 0, stream>>>(h, Wql, nullptr, qbuf, nperm, meta);
        k_hat<0><<<dim3(HTILES, HH * TEE), 256, 0, stream>>>(qbuf, Wal, qhat);
        k_typed_gemm<128, 0><<<TILES, 256, 0, stream>>>(h, Wvl, nullptr, vbuf, nperm, meta);
        k_hat<1><<<dim3(HTILES, HH * TEE), 256, 0, stream>>>(vbuf, Wml, vhat);

        k_edge<<<4096, 256, 0, stream>>>(kbuf, qhat, vhat, pri + (size_t)l * HH * TEE,
                                         offs, eidx, src, etype, agg);

        k_typed_gemm<128, 0><<<TILES, 256, 0, stream>>>(agg, Wll, nullptr, ha, nperm, meta);
        k_blend_ln<<<(NN + 3) / 4, 256, 0, stream>>>(ha, h, ntype, skip + (size_t)l * TNN,
                                                     gamma + (size_t)l * HIDD,
                                                     beta + (size_t)l * HIDD);
    }

    k_out<<<NN / 16, 256, 0, stream>>>(h, out_W, out_b, out);
}

// Round 3
// 1618.231 us; speedup vs baseline: 3.9197x; 3.9197x over previous
//
#include <hip/hip_runtime.h>
#include <hip/hip_bf16.h>
#include <math.h>

#define NN   50000
#define EE   400000
#define NINP 256
#define HH   4
#define DD   32
#define HIDD 128
#define TNN  4
#define TEE  6
#define LLL  2
#define NOUTT 16

__device__ __forceinline__ float bf_lo(unsigned u) { return __uint_as_float(u << 16); }
__device__ __forceinline__ float bf_hi(unsigned u) { return __uint_as_float(u & 0xFFFF0000u); }
__device__ __forceinline__ unsigned f2bf(float f) {
    unsigned u = __float_as_uint(f);
    u += 0x7FFFu + ((u >> 16) & 1u);
    return (u >> 16);
}

// ---------------- workspace init (replaces hipMemsetAsync) ----------------
__global__ void k_init(int* __restrict__ deg, int* __restrict__ cur, int* __restrict__ ncnt,
                       int* __restrict__ ncur, int* __restrict__ nperm) {
    int i = blockIdx.x * 256 + threadIdx.x;
    if (i < NN) { deg[i] = 0; cur[i] = 0; }
    if (i < 16) { ncnt[i] = 0; ncur[i] = 0; }
    if (i < NN + 512) nperm[i] = -1;
}

// ---------------- CSR / sort build ----------------
__global__ void k_count_edges(const int* __restrict__ dst, int* __restrict__ deg) {
    int e = blockIdx.x * 256 + threadIdx.x;
    if (e < EE) atomicAdd(&deg[dst[e]], 1);
}
__global__ void k_count_types(const int* __restrict__ ntype, int* __restrict__ ncnt) {
    int n = blockIdx.x * 256 + threadIdx.x;
    if (n < NN) atomicAdd(&ncnt[ntype[n]], 1);
}
__global__ void k_scan(const int* __restrict__ deg, int* __restrict__ offs,
                       const int* __restrict__ ncnt, int* __restrict__ meta) {
    __shared__ int s[1024];
    int tid = threadIdx.x;
    int carry = 0;
    if (tid == 0) offs[0] = 0;
    for (int base = 0; base < NN; base += 1024) {
        int i = base + tid;
        int v = (i < NN) ? deg[i] : 0;
        s[tid] = v;
        __syncthreads();
        for (int off = 1; off < 1024; off <<= 1) {
            int add = (tid >= off) ? s[tid - off] : 0;
            __syncthreads();
            s[tid] += add;
            __syncthreads();
        }
        if (i < NN) offs[i + 1] = carry + s[tid];
        carry += s[1023];
        __syncthreads();
    }
    if (tid == 0) {  // padded (to 64) row starts per node type
        int acc = 0;
        meta[0] = 0;
        for (int t = 0; t < TNN; t++) { acc += ((ncnt[t] + 63) >> 6) << 6; meta[t + 1] = acc; }
    }
}
__global__ void k_scatter_edges(const int* __restrict__ dst, const int* __restrict__ offs,
                                int* __restrict__ cur, int* __restrict__ eidx) {
    int e = blockIdx.x * 256 + threadIdx.x;
    if (e < EE) {
        int d = dst[e];
        int p = atomicAdd(&cur[d], 1);
        eidx[offs[d] + p] = e;
    }
}
__global__ void k_scatter_nodes(const int* __restrict__ ntype, const int* __restrict__ meta,
                                int* __restrict__ ncur, int* __restrict__ nperm) {
    int n = blockIdx.x * 256 + threadIdx.x;
    if (n < NN) {
        int t = ntype[n];
        int p = atomicAdd(&ncur[t], 1);
        nperm[meta[t] + p] = n;
    }
}

// ---------------- typed GEMM: Y[node] = X[node] @ W[type(node)] (+bias,gelu) ----------------
// BM=64, BN=128, BK=16, 256 threads, each thread 4 rows x 8 cols
template <int K, int EPI>
__global__ void k_typed_gemm(const float* __restrict__ X, const float* __restrict__ W,
                             const float* __restrict__ B, float* __restrict__ Y,
                             const int* __restrict__ nperm, const int* __restrict__ meta) {
    __shared__ float As[16][64];
    __shared__ float Bs[16][128];
    int tile = blockIdx.x;
    int row0 = tile * 64;
    if (row0 >= meta[4]) return;
    int t = 0;
    while (t < 3 && row0 >= meta[t + 1]) t++;
    const float* Wt = W + (size_t)t * K * 128;
    int tid = threadIdx.x;
    int am = tid & 63;
    int ak4 = (tid >> 6) * 4;
    int anode = nperm[row0 + am];
    int tr = tid & 15;
    int tc = tid >> 4;
    float acc[4][8];
#pragma unroll
    for (int i = 0; i < 4; i++)
#pragma unroll
        for (int j = 0; j < 8; j++) acc[i][j] = 0.f;

    for (int k0 = 0; k0 < K; k0 += 16) {
        float4 av = make_float4(0.f, 0.f, 0.f, 0.f);
        if (anode >= 0) av = *(const float4*)(X + (size_t)anode * K + k0 + ak4);
        As[ak4 + 0][am] = av.x; As[ak4 + 1][am] = av.y;
        As[ak4 + 2][am] = av.z; As[ak4 + 3][am] = av.w;
#pragma unroll
        for (int it = 0; it < 2; it++) {
            int idx = tid + it * 256;
            int kb = idx >> 5;
            int nb = (idx & 31) * 4;
            *(float4*)(&Bs[kb][nb]) = *(const float4*)(Wt + (size_t)(k0 + kb) * 128 + nb);
        }
        __syncthreads();
#pragma unroll
        for (int kk = 0; kk < 16; kk++) {
            float4 a4 = *(const float4*)(&As[kk][tr * 4]);
            float4 b0 = *(const float4*)(&Bs[kk][tc * 4]);
            float4 b1 = *(const float4*)(&Bs[kk][64 + tc * 4]);
            float avv[4] = {a4.x, a4.y, a4.z, a4.w};
            float bvv[8] = {b0.x, b0.y, b0.z, b0.w, b1.x, b1.y, b1.z, b1.w};
#pragma unroll
            for (int i = 0; i < 4; i++)
#pragma unroll
                for (int j = 0; j < 8; j++) acc[i][j] += avv[i] * bvv[j];
        }
        __syncthreads();
    }
#pragma unroll
    for (int i = 0; i < 4; i++) {
        int node = nperm[row0 + tr * 4 + i];
        if (node < 0) continue;
        float4 o0 = make_float4(acc[i][0], acc[i][1], acc[i][2], acc[i][3]);
        float4 o1 = make_float4(acc[i][4], acc[i][5], acc[i][6], acc[i][7]);
        if (EPI == 1) {
            const float* bt = B + t * 128;
            float4 c0 = *(const float4*)(bt + tc * 4);
            float4 c1 = *(const float4*)(bt + 64 + tc * 4);
            o0.x += c0.x; o0.y += c0.y; o0.z += c0.z; o0.w += c0.w;
            o1.x += c1.x; o1.y += c1.y; o1.z += c1.z; o1.w += c1.w;
            const float is2 = 0.70710678118654752f;
            o0.x = 0.5f * o0.x * (1.f + erff(o0.x * is2));
            o0.y = 0.5f * o0.y * (1.f + erff(o0.y * is2));
            o0.z = 0.5f * o0.z * (1.f + erff(o0.z * is2));
            o0.w = 0.5f * o0.w * (1.f + erff(o0.w * is2));
            o1.x = 0.5f * o1.x * (1.f + erff(o1.x * is2));
            o1.y = 0.5f * o1.y * (1.f + erff(o1.y * is2));
            o1.z = 0.5f * o1.z * (1.f + erff(o1.z * is2));
            o1.w = 0.5f * o1.w * (1.f + erff(o1.w * is2));
        }
        *(float4*)(Y + (size_t)node * 128 + tc * 4) = o0;
        *(float4*)(Y + (size_t)node * 128 + 64 + tc * 4) = o1;
    }
}

// ---------------- q-hat / v-hat: per (h,t) 32x32 projection, bf16 out ----------------
// MODE 0: qhat[n,gy,d] = sum_o A[n,h*32+o] * W[gy][d][o]
// MODE 1: vhat[n,gy,o] = sum_d A[n,h*32+d] * W[gy][d][o]
// Node-major thread mapping: thread = (node, 8 output cols) -> one 16B packed
// bf16x8 store per thread (round-2 profile showed 2-byte scattered stores cost
// ~32x HBM fetch+write amplification: 2.4GB fetch / 2.9GB write per launch).
template <int MODE>
__global__ void k_hat(const float* __restrict__ A, const float* __restrict__ W,
                      unsigned short* __restrict__ O) {
    __shared__ float As[64][36];  // stride 36: float4 16B-aligned, <=2-way bank conflict (free)
    __shared__ float Wt[32][36];  // Wt[j][c]: MODE0 = W[c][j] (transposed), MODE1 = W[j][c]
    int gy = blockIdx.y;
    int h = gy / TEE;
    int n0 = blockIdx.x * 64;
    int tid = threadIdx.x;
    {
        int r = tid >> 3;        // 0..31
        int c4 = (tid & 7) * 4;  // 0..28
        float4 wv = *(const float4*)(W + (size_t)gy * 1024 + r * 32 + c4);
        if (MODE == 0) {
            Wt[c4 + 0][r] = wv.x; Wt[c4 + 1][r] = wv.y;
            Wt[c4 + 2][r] = wv.z; Wt[c4 + 3][r] = wv.w;
        } else {
            *(float4*)(&Wt[r][c4]) = wv;  // (r*36+c4)*4B: 16B-aligned
        }
    }
#pragma unroll
    for (int it = 0; it < 2; it++) {
        int idx = tid + it * 256;
        int r = idx & 63;
        int j4 = (idx >> 6) * 4;
        int n = n0 + r;
        float4 av = make_float4(0.f, 0.f, 0.f, 0.f);
        if (n < NN) av = *(const float4*)(A + (size_t)n * 128 + h * 32 + j4);
        *(float4*)(&As[r][j4]) = av;  // (r*36+j4)*4B: 16B-aligned
    }
    __syncthreads();
    int nl = tid >> 2;        // local node 0..63
    int c8 = (tid & 3) * 8;   // output col group 0/8/16/24
    float acc[8];
#pragma unroll
    for (int i = 0; i < 8; i++) acc[i] = 0.f;
#pragma unroll
    for (int j = 0; j < 32; j++) {
        float a = As[nl][j];
        float4 w0 = *(const float4*)(&Wt[j][c8]);
        float4 w1 = *(const float4*)(&Wt[j][c8 + 4]);
        acc[0] += a * w0.x; acc[1] += a * w0.y; acc[2] += a * w0.z; acc[3] += a * w0.w;
        acc[4] += a * w1.x; acc[5] += a * w1.y; acc[6] += a * w1.z; acc[7] += a * w1.w;
    }
    int n = n0 + nl;
    if (n < NN) {
        uint4 pk;
        pk.x = f2bf(acc[0]) | (f2bf(acc[1]) << 16);
        pk.y = f2bf(acc[2]) | (f2bf(acc[3]) << 16);
        pk.z = f2bf(acc[4]) | (f2bf(acc[5]) << 16);
        pk.w = f2bf(acc[6]) | (f2bf(acc[7]) << 16);
        // byte addr = n*1536 + gy*64 + c8*2 -> 16B aligned, fully coalesced
        *(uint4*)(O + (size_t)n * 768 + gy * 32 + c8) = pk;
    }
}

// ---------------- fused edge pass: score + softmax(shift-free) + aggregate ----------------
// wave per dst node; lane = (h = lane>>4, pair i2 = (lane&15)*2)
__global__ void k_edge(const float* __restrict__ kbuf, const unsigned short* __restrict__ qhat,
                       const unsigned short* __restrict__ vhat, const float* __restrict__ pri,
                       const int* __restrict__ offs, const int* __restrict__ eidx,
                       const int* __restrict__ src, const int* __restrict__ etype,
                       float* __restrict__ agg) {
    int lane = threadIdx.x & 63;
    int wid = blockIdx.x * (blockDim.x >> 6) + (threadIdx.x >> 6);
    int nw = gridDim.x * (blockDim.x >> 6);
    int h = lane >> 4;
    int i2 = (lane & 15) * 2;
    const float rsD = 0.17677669529663687f;  // 1/sqrt(32)
    for (int n = wid; n < NN; n += nw) {
        int e0 = offs[n], e1 = offs[n + 1];
        float2 acc = make_float2(0.f, 0.f);
        float den = 0.f;
        const unsigned short* qrow = qhat + (size_t)n * 768;
        for (int j = e0; j < e1; j++) {
            int e = eidx[j];
            int s = src[e];
            int t = etype[e];
            float2 k2 = *(const float2*)(kbuf + (size_t)s * 128 + h * 32 + i2);
            unsigned qu = *(const unsigned*)(qrow + (h * TEE + t) * 32 + i2);
            unsigned vu = *(const unsigned*)(vhat + (size_t)s * 768 + (h * TEE + t) * 32 + i2);
            float part = k2.x * bf_lo(qu) + k2.y * bf_hi(qu);
            part += __shfl_xor(part, 1);
            part += __shfl_xor(part, 2);
            part += __shfl_xor(part, 4);
            part += __shfl_xor(part, 8);
            float ex = __expf(part * pri[h * TEE + t] * rsD);
            den += ex;
            acc.x += ex * bf_lo(vu);
            acc.y += ex * bf_hi(vu);
        }
        float r = (e1 > e0) ? (1.0f / den) : 0.f;
        *(float2*)(agg + (size_t)n * 128 + h * 32 + i2) = make_float2(acc.x * r, acc.y * r);
    }
}

// ---------------- skip-blend + LayerNorm (in-place into h) ----------------
__global__ void k_blend_ln(const float* __restrict__ ha, float* __restrict__ h,
                           const int* __restrict__ ntype, const float* __restrict__ skip,
                           const float* __restrict__ gamma, const float* __restrict__ beta) {
    int lane = threadIdx.x & 63;
    int w = threadIdx.x >> 6;
    int n = blockIdx.x * 4 + w;
    if (n >= NN) return;
    int off = lane * 2;
    int t = ntype[n];
    float alpha = 1.0f / (1.0f + __expf(-skip[t]));
    float2 a2 = *(const float2*)(ha + (size_t)n * 128 + off);
    float2 h2 = *(const float2*)(h + (size_t)n * 128 + off);
    float ox = a2.x * alpha + h2.x * (1.f - alpha);
    float oy = a2.y * alpha + h2.y * (1.f - alpha);
    float s = ox + oy;
#pragma unroll
    for (int m = 1; m < 64; m <<= 1) s += __shfl_xor(s, m);
    float mu = s * (1.0f / 128.0f);
    float dx = ox - mu, dy = oy - mu;
    float v = dx * dx + dy * dy;
#pragma unroll
    for (int m = 1; m < 64; m <<= 1) v += __shfl_xor(v, m);
    float rs = rsqrtf(v * (1.0f / 128.0f) + 1e-5f);
    float2 g2 = *(const float2*)(gamma + off);
    float2 b2 = *(const float2*)(beta + off);
    *(float2*)(h + (size_t)n * 128 + off) =
        make_float2(dx * rs * g2.x + b2.x, dy * rs * g2.y + b2.y);
}

// ---------------- output projection: out = h @ Wo + bo ----------------
__global__ void k_out(const float* __restrict__ h, const float* __restrict__ Wo,
                      const float* __restrict__ bo, float* __restrict__ out) {
    __shared__ float Ws[128 * 16];
    int tid = threadIdx.x;
#pragma unroll
    for (int it = 0; it < 2; it++) {
        int idx = (tid + it * 256) * 4;
        *(float4*)(&Ws[idx]) = *(const float4*)(Wo + idx);
    }
    __syncthreads();
    int nl = tid >> 4;
    int o = tid & 15;
    int n = blockIdx.x * 16 + nl;
    float acc = bo[o];
    const float* hr = h + (size_t)n * 128;
#pragma unroll
    for (int kk = 0; kk < 128; kk += 4) {
        float4 hv = *(const float4*)(hr + kk);
        acc += hv.x * Ws[kk * 16 + o] + hv.y * Ws[(kk + 1) * 16 + o] +
               hv.z * Ws[(kk + 2) * 16 + o] + hv.w * Ws[(kk + 3) * 16 + o];
    }
    out[(size_t)n * 16 + o] = acc;
}

extern "C" void kernel_launch(void* const* d_in, const int* in_sizes, int n_in,
                              void* d_out, int out_size, void* d_ws, size_t ws_size,
                              hipStream_t stream) {
    const float* x       = (const float*)d_in[0];
    const float* adapt_W = (const float*)d_in[1];
    const float* adapt_b = (const float*)d_in[2];
    const float* Wk      = (const float*)d_in[3];
    const float* Wq      = (const float*)d_in[4];
    const float* Wv      = (const float*)d_in[5];
    const float* pri     = (const float*)d_in[6];
    const float* Wa      = (const float*)d_in[7];
    const float* Wm      = (const float*)d_in[8];
    const float* Wla     = (const float*)d_in[9];
    const float* skip    = (const float*)d_in[10];
    const float* gamma   = (const float*)d_in[11];
    const float* beta    = (const float*)d_in[12];
    const float* out_W   = (const float*)d_in[13];
    const float* out_b   = (const float*)d_in[14];
    const int* ntype     = (const int*)d_in[15];
    const int* etype     = (const int*)d_in[16];
    const int* src       = (const int*)d_in[17];
    const int* dst       = (const int*)d_in[18];
    float* out = (float*)d_out;

    char* p = (char*)d_ws;
    auto al = [](size_t v) { return (v + 255) & ~(size_t)255; };
    size_t fsz = (size_t)NN * 128 * 4;
    float* h    = (float*)p; p += al(fsz);
    float* kbuf = (float*)p; p += al(fsz);
    float* qbuf = (float*)p; p += al(fsz);
    float* vbuf = (float*)p; p += al(fsz);
    unsigned short* qhat = (unsigned short*)p; p += al((size_t)NN * 768 * 2);
    unsigned short* vhat = (unsigned short*)p; p += al((size_t)NN * 768 * 2);
    int* deg   = (int*)p; p += al((size_t)NN * 4);
    int* offs  = (int*)p; p += al((size_t)(NN + 1) * 4);
    int* cur   = (int*)p; p += al((size_t)NN * 4);
    int* eidx  = (int*)p; p += al((size_t)EE * 4);
    int* nperm = (int*)p; p += al((size_t)(NN + 512) * 4);
    int* ncnt  = (int*)p; p += al(64);
    int* ncur  = (int*)p; p += al(64);
    int* meta  = (int*)p; p += al(64);
    float* agg = qbuf;  // qbuf dead after k_hat<0>
    float* ha  = vbuf;  // vbuf dead after k_hat<1>

    k_init<<<(NN + 512 + 255) / 256, 256, 0, stream>>>(deg, cur, ncnt, ncur, nperm);
    k_count_edges<<<(EE + 255) / 256, 256, 0, stream>>>(dst, deg);
    k_count_types<<<(NN + 255) / 256, 256, 0, stream>>>(ntype, ncnt);
    k_scan<<<1, 1024, 0, stream>>>(deg, offs, ncnt, meta);
    k_scatter_edges<<<(EE + 255) / 256, 256, 0, stream>>>(dst, offs, cur, eidx);
    k_scatter_nodes<<<(NN + 255) / 256, 256, 0, stream>>>(ntype, meta, ncur, nperm);

    const int TILES = NN / 64 + TNN + 1;  // padded tile upper bound
    const int HTILES = (NN + 63) / 64;

    k_typed_gemm<256, 1><<<TILES, 256, 0, stream>>>(x, adapt_W, adapt_b, h, nperm, meta);

    for (int l = 0; l < LLL; l++) {
        const float* Wkl = Wk + (size_t)l * TNN * HIDD * HIDD;
        const float* Wql = Wq + (size_t)l * TNN * HIDD * HIDD;
        const float* Wvl = Wv + (size_t)l * TNN * HIDD * HIDD;
        const float* Wll = Wla + (size_t)l * TNN * HIDD * HIDD;
        const float* Wal = Wa + (size_t)l * HH * TEE * DD * DD;
        const float* Wml = Wm + (size_t)l * HH * TEE * DD * DD;

        k_typed_gemm<128, 0><<<TILES, 256, 0, stream>>>(h, Wkl, nullptr, kbuf, nperm, meta);
        k_typed_gemm<128, 0><<<TILES, 256, 0, stream>>>(h, Wql, nullptr, qbuf, nperm, meta);
        k_hat<0><<<dim3(HTILES, HH * TEE), 256, 0, stream>>>(qbuf, Wal, qhat);
        k_typed_gemm<128, 0><<<TILES, 256, 0, stream>>>(h, Wvl, nullptr, vbuf, nperm, meta);
        k_hat<1><<<dim3(HTILES, HH * TEE), 256, 0, stream>>>(vbuf, Wml, vhat);

        k_edge<<<4096, 256, 0, stream>>>(kbuf, qhat, vhat, pri + (size_t)l * HH * TEE,
                                         offs, eidx, src, etype, agg);

        k_typed_gemm<128, 0><<<TILES, 256, 0, stream>>>(agg, Wll, nullptr, ha, nperm, meta);
        k_blend_ln<<<(NN + 3) / 4, 256, 0, stream>>>(ha, h, ntype, skip + (size_t)l * TNN,
                                                     gamma + (size_t)l * HIDD,
                                                     beta + (size_t)l * HIDD);
    }

    k_out<<<NN / 16, 256, 0, stream>>>(h, out_W, out_b, out);
}

// Round 4
// 1064.099 us; speedup vs baseline: 5.9610x; 1.5208x over previous
//
#include <hip/hip_runtime.h>
#include <hip/hip_bf16.h>
#include <math.h>

#define NN   50000
#define EE   400000
#define NINP 256
#define HH   4
#define DD   32
#define HIDD 128
#define TNN  4
#define TEE  6
#define LLL  2
#define NOUTT 16

__device__ __forceinline__ float bf_lo(unsigned u) { return __uint_as_float(u << 16); }
__device__ __forceinline__ float bf_hi(unsigned u) { return __uint_as_float(u & 0xFFFF0000u); }
__device__ __forceinline__ unsigned f2bf(float f) {
    unsigned u = __float_as_uint(f);
    u += 0x7FFFu + ((u >> 16) & 1u);
    return (u >> 16);
}

// ---------------- workspace init (replaces hipMemsetAsync) ----------------
__global__ void k_init(int* __restrict__ deg, int* __restrict__ cur, int* __restrict__ ncnt,
                       int* __restrict__ ncur, int* __restrict__ nperm) {
    int i = blockIdx.x * 256 + threadIdx.x;
    if (i < NN) { deg[i] = 0; cur[i] = 0; }
    if (i < 16) { ncnt[i] = 0; ncur[i] = 0; }
    if (i < NN + 512) nperm[i] = -1;
}

// ---------------- CSR / sort build ----------------
__global__ void k_count_edges(const int* __restrict__ dst, int* __restrict__ deg) {
    int e = blockIdx.x * 256 + threadIdx.x;
    if (e < EE) atomicAdd(&deg[dst[e]], 1);
}
// wave-aggregated: 1 atomic per (wave,type) instead of 1 per node
// (round-3 profile: 50k atomics / 4 addrs serialized ~250us in scatter variant)
__global__ void k_count_types(const int* __restrict__ ntype, int* __restrict__ ncnt) {
    int n = blockIdx.x * 256 + threadIdx.x;
    int lane = threadIdx.x & 63;
    int t = (n < NN) ? ntype[n] : -1;
#pragma unroll
    for (int tt = 0; tt < TNN; tt++) {
        unsigned long long mask = __ballot(t == tt);
        if (mask && lane == (__ffsll((unsigned long long)mask) - 1))
            atomicAdd(&ncnt[tt], __popcll(mask));
    }
}
// two-level shuffle scan: 3 barriers/iter (was ~20 with LDS ladder)
__global__ void k_scan(const int* __restrict__ deg, int* __restrict__ offs,
                       const int* __restrict__ ncnt, int* __restrict__ meta) {
    __shared__ int wsum[16];
    int tid = threadIdx.x;
    int lane = tid & 63;
    int wv = tid >> 6;
    int carry = 0;
    if (tid == 0) offs[0] = 0;
    for (int base = 0; base < NN; base += 1024) {
        int i = base + tid;
        int x = (i < NN) ? deg[i] : 0;
#pragma unroll
        for (int off = 1; off < 64; off <<= 1) {
            int y = __shfl_up(x, off);
            if (lane >= off) x += y;
        }
        if (lane == 63) wsum[wv] = x;
        __syncthreads();
        if (wv == 0 && lane < 16) {
            int s = wsum[lane];
#pragma unroll
            for (int off = 1; off < 16; off <<= 1) {
                int y = __shfl_up(s, off);
                if (lane >= off) s += y;
            }
            wsum[lane] = s;
        }
        __syncthreads();
        int wbase = (wv == 0) ? 0 : wsum[wv - 1];
        if (i < NN) offs[i + 1] = carry + wbase + x;
        carry += wsum[15];
        __syncthreads();
    }
    if (tid == 0) {  // padded (to 64) row starts per node type
        int acc = 0;
        meta[0] = 0;
        for (int t = 0; t < TNN; t++) { acc += ((ncnt[t] + 63) >> 6) << 6; meta[t + 1] = acc; }
    }
}
__global__ void k_scatter_edges(const int* __restrict__ dst, const int* __restrict__ offs,
                                int* __restrict__ cur, int* __restrict__ eidx) {
    int e = blockIdx.x * 256 + threadIdx.x;
    if (e < EE) {
        int d = dst[e];
        int p = atomicAdd(&cur[d], 1);
        eidx[offs[d] + p] = e;
    }
}
// wave-aggregated scatter: ballot per type, one atomic per (wave,type), rank from mask
__global__ void k_scatter_nodes(const int* __restrict__ ntype, const int* __restrict__ meta,
                                int* __restrict__ ncur, int* __restrict__ nperm) {
    int n = blockIdx.x * 256 + threadIdx.x;
    int lane = threadIdx.x & 63;
    int t = (n < NN) ? ntype[n] : -1;
#pragma unroll
    for (int tt = 0; tt < TNN; tt++) {
        unsigned long long mask = __ballot(t == tt);
        if (t == tt) {
            int rank = __popcll(mask & ((1ull << lane) - 1ull));
            int leader = __ffsll((unsigned long long)mask) - 1;
            int b = 0;
            if (rank == 0) b = atomicAdd(&ncur[tt], __popcll(mask));
            b = __shfl(b, leader);
            nperm[meta[tt] + b + rank] = n;
        }
    }
}

// ---------------- typed GEMM: Y[node] = X[node] @ W[type(node)] (+bias,gelu) ----------------
// BM=64, BN=128, BK=16, 256 threads, each thread 4 rows x 8 cols
template <int K, int EPI>
__global__ void k_typed_gemm(const float* __restrict__ X, const float* __restrict__ W,
                             const float* __restrict__ B, float* __restrict__ Y,
                             const int* __restrict__ nperm, const int* __restrict__ meta) {
    __shared__ float As[16][64];
    __shared__ float Bs[16][128];
    int tile = blockIdx.x;
    int row0 = tile * 64;
    if (row0 >= meta[4]) return;
    int t = 0;
    while (t < 3 && row0 >= meta[t + 1]) t++;
    const float* Wt = W + (size_t)t * K * 128;
    int tid = threadIdx.x;
    int am = tid & 63;
    int ak4 = (tid >> 6) * 4;
    int anode = nperm[row0 + am];
    int tr = tid & 15;
    int tc = tid >> 4;
    float acc[4][8];
#pragma unroll
    for (int i = 0; i < 4; i++)
#pragma unroll
        for (int j = 0; j < 8; j++) acc[i][j] = 0.f;

    for (int k0 = 0; k0 < K; k0 += 16) {
        float4 av = make_float4(0.f, 0.f, 0.f, 0.f);
        if (anode >= 0) av = *(const float4*)(X + (size_t)anode * K + k0 + ak4);
        As[ak4 + 0][am] = av.x; As[ak4 + 1][am] = av.y;
        As[ak4 + 2][am] = av.z; As[ak4 + 3][am] = av.w;
#pragma unroll
        for (int it = 0; it < 2; it++) {
            int idx = tid + it * 256;
            int kb = idx >> 5;
            int nb = (idx & 31) * 4;
            *(float4*)(&Bs[kb][nb]) = *(const float4*)(Wt + (size_t)(k0 + kb) * 128 + nb);
        }
        __syncthreads();
#pragma unroll
        for (int kk = 0; kk < 16; kk++) {
            float4 a4 = *(const float4*)(&As[kk][tr * 4]);
            float4 b0 = *(const float4*)(&Bs[kk][tc * 4]);
            float4 b1 = *(const float4*)(&Bs[kk][64 + tc * 4]);
            float avv[4] = {a4.x, a4.y, a4.z, a4.w};
            float bvv[8] = {b0.x, b0.y, b0.z, b0.w, b1.x, b1.y, b1.z, b1.w};
#pragma unroll
            for (int i = 0; i < 4; i++)
#pragma unroll
                for (int j = 0; j < 8; j++) acc[i][j] += avv[i] * bvv[j];
        }
        __syncthreads();
    }
#pragma unroll
    for (int i = 0; i < 4; i++) {
        int node = nperm[row0 + tr * 4 + i];
        if (node < 0) continue;
        float4 o0 = make_float4(acc[i][0], acc[i][1], acc[i][2], acc[i][3]);
        float4 o1 = make_float4(acc[i][4], acc[i][5], acc[i][6], acc[i][7]);
        if (EPI == 1) {
            const float* bt = B + t * 128;
            float4 c0 = *(const float4*)(bt + tc * 4);
            float4 c1 = *(const float4*)(bt + 64 + tc * 4);
            o0.x += c0.x; o0.y += c0.y; o0.z += c0.z; o0.w += c0.w;
            o1.x += c1.x; o1.y += c1.y; o1.z += c1.z; o1.w += c1.w;
            const float is2 = 0.70710678118654752f;
            o0.x = 0.5f * o0.x * (1.f + erff(o0.x * is2));
            o0.y = 0.5f * o0.y * (1.f + erff(o0.y * is2));
            o0.z = 0.5f * o0.z * (1.f + erff(o0.z * is2));
            o0.w = 0.5f * o0.w * (1.f + erff(o0.w * is2));
            o1.x = 0.5f * o1.x * (1.f + erff(o1.x * is2));
            o1.y = 0.5f * o1.y * (1.f + erff(o1.y * is2));
            o1.z = 0.5f * o1.z * (1.f + erff(o1.z * is2));
            o1.w = 0.5f * o1.w * (1.f + erff(o1.w * is2));
        }
        *(float4*)(Y + (size_t)node * 128 + tc * 4) = o0;
        *(float4*)(Y + (size_t)node * 128 + 64 + tc * 4) = o1;
    }
}

// ---------------- q-hat / v-hat: per (h,t) 32x32 projection, bf16 out ----------------
// MODE 0: qhat[n,gy,d] = sum_o A[n,h*32+o] * W[gy][d][o]
// MODE 1: vhat[n,gy,o] = sum_d A[n,h*32+d] * W[gy][d][o]
// Node-major mapping -> one 16B packed bf16x8 store per thread (fully coalesced).
template <int MODE>
__global__ void k_hat(const float* __restrict__ A, const float* __restrict__ W,
                      unsigned short* __restrict__ O) {
    __shared__ float As[64][36];  // stride 36: float4 16B-aligned, <=2-way conflict (free)
    __shared__ float Wt[32][36];  // Wt[j][c]: MODE0 = W[c][j] (transposed), MODE1 = W[j][c]
    int gy = blockIdx.y;
    int h = gy / TEE;
    int n0 = blockIdx.x * 64;
    int tid = threadIdx.x;
    {
        int r = tid >> 3;        // 0..31
        int c4 = (tid & 7) * 4;  // 0..28
        float4 wv = *(const float4*)(W + (size_t)gy * 1024 + r * 32 + c4);
        if (MODE == 0) {
            Wt[c4 + 0][r] = wv.x; Wt[c4 + 1][r] = wv.y;
            Wt[c4 + 2][r] = wv.z; Wt[c4 + 3][r] = wv.w;
        } else {
            *(float4*)(&Wt[r][c4]) = wv;
        }
    }
#pragma unroll
    for (int it = 0; it < 2; it++) {
        int idx = tid + it * 256;
        int r = idx & 63;
        int j4 = (idx >> 6) * 4;
        int n = n0 + r;
        float4 av = make_float4(0.f, 0.f, 0.f, 0.f);
        if (n < NN) av = *(const float4*)(A + (size_t)n * 128 + h * 32 + j4);
        *(float4*)(&As[r][j4]) = av;
    }
    __syncthreads();
    int nl = tid >> 2;        // local node 0..63
    int c8 = (tid & 3) * 8;   // output col group 0/8/16/24
    float acc[8];
#pragma unroll
    for (int i = 0; i < 8; i++) acc[i] = 0.f;
#pragma unroll
    for (int j = 0; j < 32; j++) {
        float a = As[nl][j];
        float4 w0 = *(const float4*)(&Wt[j][c8]);
        float4 w1 = *(const float4*)(&Wt[j][c8 + 4]);
        acc[0] += a * w0.x; acc[1] += a * w0.y; acc[2] += a * w0.z; acc[3] += a * w0.w;
        acc[4] += a * w1.x; acc[5] += a * w1.y; acc[6] += a * w1.z; acc[7] += a * w1.w;
    }
    int n = n0 + nl;
    if (n < NN) {
        uint4 pk;
        pk.x = f2bf(acc[0]) | (f2bf(acc[1]) << 16);
        pk.y = f2bf(acc[2]) | (f2bf(acc[3]) << 16);
        pk.z = f2bf(acc[4]) | (f2bf(acc[5]) << 16);
        pk.w = f2bf(acc[6]) | (f2bf(acc[7]) << 16);
        *(uint4*)(O + (size_t)n * 768 + gy * 32 + c8) = pk;
    }
}

// ---------------- fused edge pass: score + softmax(shift-free) + aggregate ----------------
__global__ void k_edge(const float* __restrict__ kbuf, const unsigned short* __restrict__ qhat,
                       const unsigned short* __restrict__ vhat, const float* __restrict__ pri,
                       const int* __restrict__ offs, const int* __restrict__ eidx,
                       const int* __restrict__ src, const int* __restrict__ etype,
                       float* __restrict__ agg) {
    int lane = threadIdx.x & 63;
    int wid = blockIdx.x * (blockDim.x >> 6) + (threadIdx.x >> 6);
    int nw = gridDim.x * (blockDim.x >> 6);
    int h = lane >> 4;
    int i2 = (lane & 15) * 2;
    const float rsD = 0.17677669529663687f;  // 1/sqrt(32)
    for (int n = wid; n < NN; n += nw) {
        int e0 = offs[n], e1 = offs[n + 1];
        float2 acc = make_float2(0.f, 0.f);
        float den = 0.f;
        const unsigned short* qrow = qhat + (size_t)n * 768;
        for (int j = e0; j < e1; j++) {
            int e = eidx[j];
            int s = src[e];
            int t = etype[e];
            float2 k2 = *(const float2*)(kbuf + (size_t)s * 128 + h * 32 + i2);
            unsigned qu = *(const unsigned*)(qrow + (h * TEE + t) * 32 + i2);
            unsigned vu = *(const unsigned*)(vhat + (size_t)s * 768 + (h * TEE + t) * 32 + i2);
            float part = k2.x * bf_lo(qu) + k2.y * bf_hi(qu);
            part += __shfl_xor(part, 1);
            part += __shfl_xor(part, 2);
            part += __shfl_xor(part, 4);
            part += __shfl_xor(part, 8);
            float ex = __expf(part * pri[h * TEE + t] * rsD);
            den += ex;
            acc.x += ex * bf_lo(vu);
            acc.y += ex * bf_hi(vu);
        }
        float r = (e1 > e0) ? (1.0f / den) : 0.f;
        *(float2*)(agg + (size_t)n * 128 + h * 32 + i2) = make_float2(acc.x * r, acc.y * r);
    }
}

// ---------------- skip-blend + LayerNorm (in-place into h) ----------------
__global__ void k_blend_ln(const float* __restrict__ ha, float* __restrict__ h,
                           const int* __restrict__ ntype, const float* __restrict__ skip,
                           const float* __restrict__ gamma, const float* __restrict__ beta) {
    int lane = threadIdx.x & 63;
    int w = threadIdx.x >> 6;
    int n = blockIdx.x * 4 + w;
    if (n >= NN) return;
    int off = lane * 2;
    int t = ntype[n];
    float alpha = 1.0f / (1.0f + __expf(-skip[t]));
    float2 a2 = *(const float2*)(ha + (size_t)n * 128 + off);
    float2 h2 = *(const float2*)(h + (size_t)n * 128 + off);
    float ox = a2.x * alpha + h2.x * (1.f - alpha);
    float oy = a2.y * alpha + h2.y * (1.f - alpha);
    float s = ox + oy;
#pragma unroll
    for (int m = 1; m < 64; m <<= 1) s += __shfl_xor(s, m);
    float mu = s * (1.0f / 128.0f);
    float dx = ox - mu, dy = oy - mu;
    float v = dx * dx + dy * dy;
#pragma unroll
    for (int m = 1; m < 64; m <<= 1) v += __shfl_xor(v, m);
    float rs = rsqrtf(v * (1.0f / 128.0f) + 1e-5f);
    float2 g2 = *(const float2*)(gamma + off);
    float2 b2 = *(const float2*)(beta + off);
    *(float2*)(h + (size_t)n * 128 + off) =
        make_float2(dx * rs * g2.x + b2.x, dy * rs * g2.y + b2.y);
}

// ---------------- output projection: out = h @ Wo + bo ----------------
__global__ void k_out(const float* __restrict__ h, const float* __restrict__ Wo,
                      const float* __restrict__ bo, float* __restrict__ out) {
    __shared__ float Ws[128 * 16];
    int tid = threadIdx.x;
#pragma unroll
    for (int it = 0; it < 2; it++) {
        int idx = (tid + it * 256) * 4;
        *(float4*)(&Ws[idx]) = *(const float4*)(Wo + idx);
    }
    __syncthreads();
    int nl = tid >> 4;
    int o = tid & 15;
    int n = blockIdx.x * 16 + nl;
    float acc = bo[o];
    const float* hr = h + (size_t)n * 128;
#pragma unroll
    for (int kk = 0; kk < 128; kk += 4) {
        float4 hv = *(const float4*)(hr + kk);
        acc += hv.x * Ws[kk * 16 + o] + hv.y * Ws[(kk + 1) * 16 + o] +
               hv.z * Ws[(kk + 2) * 16 + o] + hv.w * Ws[(kk + 3) * 16 + o];
    }
    out[(size_t)n * 16 + o] = acc;
}

extern "C" void kernel_launch(void* const* d_in, const int* in_sizes, int n_in,
                              void* d_out, int out_size, void* d_ws, size_t ws_size,
                              hipStream_t stream) {
    const float* x       = (const float*)d_in[0];
    const float* adapt_W = (const float*)d_in[1];
    const float* adapt_b = (const float*)d_in[2];
    const float* Wk      = (const float*)d_in[3];
    const float* Wq      = (const float*)d_in[4];
    const float* Wv      = (const float*)d_in[5];
    const float* pri     = (const float*)d_in[6];
    const float* Wa      = (const float*)d_in[7];
    const float* Wm      = (const float*)d_in[8];
    const float* Wla     = (const float*)d_in[9];
    const float* skip    = (const float*)d_in[10];
    const float* gamma   = (const float*)d_in[11];
    const float* beta    = (const float*)d_in[12];
    const float* out_W   = (const float*)d_in[13];
    const float* out_b   = (const float*)d_in[14];
    const int* ntype     = (const int*)d_in[15];
    const int* etype     = (const int*)d_in[16];
    const int* src       = (const int*)d_in[17];
    const int* dst       = (const int*)d_in[18];
    float* out = (float*)d_out;

    char* p = (char*)d_ws;
    auto al = [](size_t v) { return (v + 255) & ~(size_t)255; };
    size_t fsz = (size_t)NN * 128 * 4;
    float* h    = (float*)p; p += al(fsz);
    float* kbuf = (float*)p; p += al(fsz);
    float* qbuf = (float*)p; p += al(fsz);
    float* vbuf = (float*)p; p += al(fsz);
    unsigned short* qhat = (unsigned short*)p; p += al((size_t)NN * 768 * 2);
    unsigned short* vhat = (unsigned short*)p; p += al((size_t)NN * 768 * 2);
    int* deg   = (int*)p; p += al((size_t)NN * 4);
    int* offs  = (int*)p; p += al((size_t)(NN + 1) * 4);
    int* cur   = (int*)p; p += al((size_t)NN * 4);
    int* eidx  = (int*)p; p += al((size_t)EE * 4);
    int* nperm = (int*)p; p += al((size_t)(NN + 512) * 4);
    int* ncnt  = (int*)p; p += al(64);
    int* ncur  = (int*)p; p += al(64);
    int* meta  = (int*)p; p += al(64);
    float* agg = qbuf;  // qbuf dead after k_hat<0>
    float* ha  = vbuf;  // vbuf dead after k_hat<1>

    k_init<<<(NN + 512 + 255) / 256, 256, 0, stream>>>(deg, cur, ncnt, ncur, nperm);
    k_count_edges<<<(EE + 255) / 256, 256, 0, stream>>>(dst, deg);
    k_count_types<<<(NN + 255) / 256, 256, 0, stream>>>(ntype, ncnt);
    k_scan<<<1, 1024, 0, stream>>>(deg, offs, ncnt, meta);
    k_scatter_edges<<<(EE + 255) / 256, 256, 0, stream>>>(dst, offs, cur, eidx);
    k_scatter_nodes<<<(NN + 255) / 256, 256, 0, stream>>>(ntype, meta, ncur, nperm);

    const int TILES = NN / 64 + TNN + 1;  // padded tile upper bound
    const int HTILES = (NN + 63) / 64;

    k_typed_gemm<256, 1><<<TILES, 256, 0, stream>>>(x, adapt_W, adapt_b, h, nperm, meta);

    for (int l = 0; l < LLL; l++) {
        const float* Wkl = Wk + (size_t)l * TNN * HIDD * HIDD;
        const float* Wql = Wq + (size_t)l * TNN * HIDD * HIDD;
        const float* Wvl = Wv + (size_t)l * TNN * HIDD * HIDD;
        const float* Wll = Wla + (size_t)l * TNN * HIDD * HIDD;
        const float* Wal = Wa + (size_t)l * HH * TEE * DD * DD;
        const float* Wml = Wm + (size_t)l * HH * TEE * DD * DD;

        k_typed_gemm<128, 0><<<TILES, 256, 0, stream>>>(h, Wkl, nullptr, kbuf, nperm, meta);
        k_typed_gemm<128, 0><<<TILES, 256, 0, stream>>>(h, Wql, nullptr, qbuf, nperm, meta);
        k_hat<0><<<dim3(HTILES, HH * TEE), 256, 0, stream>>>(qbuf, Wal, qhat);
        k_typed_gemm<128, 0><<<TILES, 256, 0, stream>>>(h, Wvl, nullptr, vbuf, nperm, meta);
        k_hat<1><<<dim3(HTILES, HH * TEE), 256, 0, stream>>>(vbuf, Wml, vhat);

        k_edge<<<4096, 256, 0, stream>>>(kbuf, qhat, vhat, pri + (size_t)l * HH * TEE,
                                         offs, eidx, src, etype, agg);

        k_typed_gemm<128, 0><<<TILES, 256, 0, stream>>>(agg, Wll, nullptr, ha, nperm, meta);
        k_blend_ln<<<(NN + 3) / 4, 256, 0, stream>>>(ha, h, ntype, skip + (size_t)l * TNN,
                                                     gamma + (size_t)l * HIDD,
                                                     beta + (size_t)l * HIDD);
    }

    k_out<<<NN / 16, 256, 0, stream>>>(h, out_W, out_b, out);
}

// Round 7
// 798.371 us; speedup vs baseline: 7.9450x; 1.3328x over previous
//
#include <hip/hip_runtime.h>
#include <hip/hip_bf16.h>
#include <math.h>

#define NN   50000
#define EE   400000
#define NINP 256
#define HH   4
#define DD   32
#define HIDD 128
#define TNN  4
#define TEE  6
#define LLL  2
#define NOUTT 16

// RULE (cost us two crashed rounds): every LDS array row stride must be a
// multiple of 4 fp32 / 8 bf16 elements so vector b128 accesses stay 16B-aligned.
// RULE (round 6): every LDS staging loop must cover rows*cols/threads slots —
// audit `it` trip counts when copying loops between kernels.

typedef __attribute__((ext_vector_type(8))) short bf16x8;
typedef __attribute__((ext_vector_type(4))) float f32x4;

__device__ __forceinline__ float bf_lo(unsigned u) { return __uint_as_float(u << 16); }
__device__ __forceinline__ float bf_hi(unsigned u) { return __uint_as_float(u & 0xFFFF0000u); }
__device__ __forceinline__ unsigned f2bf(float f) {
    unsigned u = __float_as_uint(f);
    u += 0x7FFFu + ((u >> 16) & 1u);
    return (u >> 16);
}

// ---------------- workspace init ----------------
__global__ void k_init(int* __restrict__ deg, int* __restrict__ cur, int* __restrict__ ncnt,
                       int* __restrict__ ncur, int* __restrict__ nperm) {
    int i = blockIdx.x * 256 + threadIdx.x;
    if (i < NN) { deg[i] = 0; cur[i] = 0; }
    if (i < 16) { ncnt[i] = 0; ncur[i] = 0; }
    if (i < NN + 512) nperm[i] = -1;
}

// ---------------- CSR / sort build ----------------
__global__ void k_count_edges(const int* __restrict__ dst, int* __restrict__ deg) {
    int e = blockIdx.x * 256 + threadIdx.x;
    if (e < EE) atomicAdd(&deg[dst[e]], 1);
}
__global__ void k_count_types(const int* __restrict__ ntype, int* __restrict__ ncnt) {
    int n = blockIdx.x * 256 + threadIdx.x;
    int lane = threadIdx.x & 63;
    int t = (n < NN) ? ntype[n] : -1;
#pragma unroll
    for (int tt = 0; tt < TNN; tt++) {
        unsigned long long mask = __ballot(t == tt);
        if (mask && lane == (__ffsll((unsigned long long)mask) - 1))
            atomicAdd(&ncnt[tt], __popcll(mask));
    }
}
__global__ void k_scan(const int* __restrict__ deg, int* __restrict__ offs,
                       const int* __restrict__ ncnt, int* __restrict__ meta) {
    __shared__ int wsum[16];
    int tid = threadIdx.x;
    int lane = tid & 63;
    int wv = tid >> 6;
    int carry = 0;
    if (tid == 0) offs[0] = 0;
    for (int base = 0; base < NN; base += 1024) {
        int i = base + tid;
        int x = (i < NN) ? deg[i] : 0;
#pragma unroll
        for (int off = 1; off < 64; off <<= 1) {
            int y = __shfl_up(x, off);
            if (lane >= off) x += y;
        }
        if (lane == 63) wsum[wv] = x;
        __syncthreads();
        if (wv == 0 && lane < 16) {
            int s = wsum[lane];
#pragma unroll
            for (int off = 1; off < 16; off <<= 1) {
                int y = __shfl_up(s, off);
                if (lane >= off) s += y;
            }
            wsum[lane] = s;
        }
        __syncthreads();
        int wbase = (wv == 0) ? 0 : wsum[wv - 1];
        if (i < NN) offs[i + 1] = carry + wbase + x;
        carry += wsum[15];
        __syncthreads();
    }
    if (tid == 0) {
        int acc = 0;
        meta[0] = 0;
        for (int t = 0; t < TNN; t++) { acc += ((ncnt[t] + 63) >> 6) << 6; meta[t + 1] = acc; }
    }
}
__global__ void k_scatter_edges(const int* __restrict__ dst, const int* __restrict__ offs,
                                int* __restrict__ cur, int* __restrict__ eidx) {
    int e = blockIdx.x * 256 + threadIdx.x;
    if (e < EE) {
        int d = dst[e];
        int p = atomicAdd(&cur[d], 1);
        eidx[offs[d] + p] = e;
    }
}
__global__ void k_scatter_nodes(const int* __restrict__ ntype, const int* __restrict__ meta,
                                int* __restrict__ ncur, int* __restrict__ nperm) {
    int n = blockIdx.x * 256 + threadIdx.x;
    int lane = threadIdx.x & 63;
    int t = (n < NN) ? ntype[n] : -1;
#pragma unroll
    for (int tt = 0; tt < TNN; tt++) {
        unsigned long long mask = __ballot(t == tt);
        if (t == tt) {
            int rank = __popcll(mask & ((1ull << lane) - 1ull));
            int leader = __ffsll((unsigned long long)mask) - 1;
            int b = 0;
            if (rank == 0) b = atomicAdd(&ncur[tt], __popcll(mask));
            b = __shfl(b, leader);
            nperm[meta[tt] + b + rank] = n;
        }
    }
}

// ---------------- x -> bf16 ----------------
__global__ void k_cvt_x(const float* __restrict__ x, unsigned short* __restrict__ xb) {
    size_t i = ((size_t)blockIdx.x * 256 + threadIdx.x) * 8;
    float4 a = *(const float4*)(x + i);
    float4 b = *(const float4*)(x + i + 4);
    uint4 pk;
    pk.x = f2bf(a.x) | (f2bf(a.y) << 16);
    pk.y = f2bf(a.z) | (f2bf(a.w) << 16);
    pk.z = f2bf(b.x) | (f2bf(b.y) << 16);
    pk.w = f2bf(b.z) | (f2bf(b.w) << 16);
    *(uint4*)(xb + i) = pk;
}

// ---------------- weight transpose+convert: W[t][k][n] f32 -> WT[t][n][k] bf16 ----------
__global__ void k_wt(const float* __restrict__ adapt_W, const float* __restrict__ Wk,
                     const float* __restrict__ Wla, unsigned short* __restrict__ adaptT,
                     unsigned short* __restrict__ WkT, unsigned short* __restrict__ WlaT) {
    __shared__ float Ts[64][68];  // 68*4=272B row stride, 16B multiple
    int b = blockIdx.x, tid = threadIdx.x;
    const float* src;
    unsigned short* dst;
    int K, kt, nt;
    if (b < 32) {
        int t = b >> 3, tile = b & 7;
        K = 256; kt = tile >> 1; nt = tile & 1;
        src = adapt_W + (size_t)t * 256 * 128;
        dst = adaptT + (size_t)t * 128 * 256;
    } else if (b < 64) {
        int b2 = b - 32, l = b2 >> 4, r = b2 & 15, t = r >> 2, tile = r & 3;
        K = 128; kt = tile >> 1; nt = tile & 1;
        src = Wk + (size_t)(l * 4 + t) * 16384;
        dst = WkT + (size_t)(l * 4 + t) * 16384;
    } else {
        int b2 = b - 64, l = b2 >> 4, r = b2 & 15, t = r >> 2, tile = r & 3;
        K = 128; kt = tile >> 1; nt = tile & 1;
        src = Wla + (size_t)(l * 4 + t) * 16384;
        dst = WlaT + (size_t)(l * 4 + t) * 16384;
    }
    int k0 = kt * 64, n0 = nt * 64;
#pragma unroll
    for (int it = 0; it < 4; it++) {  // 64 rows x 16 slots = 1024 = 256*4
        int idx = tid + it * 256;
        int row = idx >> 4, c4 = (idx & 15) * 4;
        *(float4*)(&Ts[row][c4]) = *(const float4*)(src + (size_t)(k0 + row) * 128 + n0 + c4);
    }
    __syncthreads();
#pragma unroll
    for (int it = 0; it < 2; it++) {  // 64 rows x 8 slots = 512 = 256*2
        int idx = tid + it * 256;
        int nn = idx >> 3, sg = (idx & 7) * 8;
        uint4 pk;
        pk.x = f2bf(Ts[sg + 0][nn]) | (f2bf(Ts[sg + 1][nn]) << 16);
        pk.y = f2bf(Ts[sg + 2][nn]) | (f2bf(Ts[sg + 3][nn]) << 16);
        pk.z = f2bf(Ts[sg + 4][nn]) | (f2bf(Ts[sg + 5][nn]) << 16);
        pk.w = f2bf(Ts[sg + 6][nn]) | (f2bf(Ts[sg + 7][nn]) << 16);
        *(uint4*)(dst + (size_t)(n0 + nn) * K + k0 + sg) = pk;
    }
}

// ---------------- combined weights ----------------
// combQ[t][j=(h,te,d)][k] = sum_o Wq[l][t][k][h*32+o]*Wa[l][h][te][d][o] * pri/sqrtD
// combV[t][j=(h,te,o)][k] = sum_d Wv[l][t][k][h*32+d]*Wm[l][h][te][d][o]
__global__ void k_comb(const float* __restrict__ Wq, const float* __restrict__ Wa,
                       const float* __restrict__ Wv, const float* __restrict__ Wm,
                       const float* __restrict__ pri, unsigned short* __restrict__ combQ,
                       unsigned short* __restrict__ combV) {
    __shared__ float Ls[128][36];       // stride 36: 16B-aligned float4 rows
    __shared__ float Ss[32][36];
    __shared__ unsigned short Ot[32][136];
    int b = blockIdx.x, tid = threadIdx.x;
    int mode = b / 192;
    int rem = b % 192;
    int l = rem / 96;
    int rem2 = rem % 96;
    int t = rem2 / 24;
    int ht = rem2 % 24;
    int hh = ht / 6, te = ht % 6;
    const float* L = (mode == 0 ? Wq : Wv) + ((size_t)(l * TNN + t)) * 16384;  // [128][128]
    const float* S = (mode == 0 ? Wa : Wm) + ((size_t)((l * HH + hh) * TEE + te)) * 1024;
    float ps = (mode == 0) ? pri[(l * HH + hh) * TEE + te] * 0.17677669529663687f : 1.0f;
#pragma unroll
    for (int it = 0; it < 4; it++) {  // ROUND-6 BUG WAS HERE: 128 rows x 8 slots = 1024 = 256*4 (was *2 -> half of Ls garbage)
        int idx = tid + it * 256;
        int kk = idx >> 3, c4 = (idx & 7) * 4;
        *(float4*)(&Ls[kk][c4]) = *(const float4*)(L + (size_t)kk * 128 + hh * 32 + c4);
    }
    {
        int r = tid >> 3, c4 = (tid & 7) * 4;  // 32 rows x 8 slots = 256
        *(float4*)(&Ss[r][c4]) = *(const float4*)(S + r * 32 + c4);
    }
    __syncthreads();
    int k = tid >> 1, half = tid & 1;
#pragma unroll
    for (int jj = 0; jj < 16; jj++) {
        int j = half * 16 + jj;
        float s = 0.f;
        if (mode == 0) {
#pragma unroll
            for (int o = 0; o < 32; o++) s += Ls[k][o] * Ss[j][o];
        } else {
#pragma unroll
            for (int d = 0; d < 32; d++) s += Ls[k][d] * Ss[d][j];
        }
        Ot[j][k] = (unsigned short)f2bf(s * ps);
    }
    __syncthreads();
    unsigned short* dst = (mode == 0 ? combQ : combV) + (size_t)l * TNN * 768 * 128;
#pragma unroll
    for (int it = 0; it < 2; it++) {  // 32 rows x 16 slots = 512 = 256*2
        int idx = tid + it * 256;
        int j = idx >> 4, sg = (idx & 15) * 8;
        uint4 pk = *(const uint4*)(&Ot[j][sg]);
        int jg = (hh * 6 + te) * 32 + j;
        *(uint4*)(dst + ((size_t)t * 768 + jg) * 128 + sg) = pk;
    }
}

// ---------------- MFMA typed GEMM ----------------
// Y[node] = A[node] @ WT[type]^T ; A bf16 [node][K], WT bf16 [t][NCB*128][K]
// EPI: 1 = +bias, exact gelu. OMODE: 0 fp32 out, 1 bf16 out, 2 both
template <int K, int NCB, int EPI, int OMODE>
__launch_bounds__(256) __global__
void k_gemm(const unsigned short* __restrict__ A, const unsigned short* __restrict__ WT,
            const float* __restrict__ bias, float* __restrict__ Yf,
            unsigned short* __restrict__ Yb, const int* __restrict__ nperm,
            const int* __restrict__ meta) {
    __shared__ __align__(16) char smem[52224];
    unsigned short* Ab = (unsigned short*)smem;            // [64][136] bf16 (272B stride)
    unsigned short* Bs = (unsigned short*)(smem + 17408);  // [128][136] bf16
    float* Cb = (float*)(smem + 17408);                    // [64][132] f32 (528B stride, aliases Bs)
    const int WIDTH = NCB * 128;
    int row0 = blockIdx.x * 64;
    if (row0 >= meta[4]) return;
    int t = 0;
    while (t < 3 && row0 >= meta[t + 1]) t++;
    const unsigned short* WTt = WT + (size_t)t * WIDTH * K;
    int tid = threadIdx.x;
    int lane = tid & 63, w = tid >> 6;
    int m = lane & 15, q = lane >> 4;

#pragma unroll
    for (int cb = 0; cb < NCB; cb++) {
        f32x4 acc[8];
#pragma unroll
        for (int g = 0; g < 8; g++) acc[g] = (f32x4){0.f, 0.f, 0.f, 0.f};
#pragma unroll
        for (int kc = 0; kc < K / 128; kc++) {
            __syncthreads();  // prior epilogue reads of Cb(=Bs) done
            if (NCB == 1 || cb == 0) {
#pragma unroll
                for (int it = 0; it < 4; it++) {  // 64 rows x 16 slots
                    int idx = tid + it * 256;
                    int r = idx >> 4, sg = idx & 15;
                    int node = nperm[row0 + r];
                    uint4 v = make_uint4(0, 0, 0, 0);
                    if (node >= 0) v = *(const uint4*)(A + (size_t)node * K + kc * 128 + sg * 8);
                    *(uint4*)(Ab + r * 136 + sg * 8) = v;
                }
            }
#pragma unroll
            for (int it = 0; it < 8; it++) {  // 128 rows x 16 slots
                int idx = tid + it * 256;
                int n = idx >> 4, sg = idx & 15;
                *(uint4*)(Bs + n * 136 + sg * 8) =
                    *(const uint4*)(WTt + (size_t)(cb * 128 + n) * K + kc * 128 + sg * 8);
            }
            __syncthreads();
#pragma unroll
            for (int k0 = 0; k0 < 128; k0 += 32) {
                bf16x8 a = *(const bf16x8*)(Ab + (w * 16 + m) * 136 + k0 + q * 8);
#pragma unroll
                for (int g = 0; g < 8; g++) {
                    bf16x8 bb = *(const bf16x8*)(Bs + (g * 16 + m) * 136 + k0 + q * 8);
                    acc[g] = __builtin_amdgcn_mfma_f32_16x16x32_bf16(a, bb, acc[g], 0, 0, 0);
                }
            }
        }
        __syncthreads();  // mfma LDS reads done before Cb (alias Bs) write
#pragma unroll
        for (int g = 0; g < 8; g++)
#pragma unroll
            for (int r = 0; r < 4; r++)
                Cb[(w * 16 + q * 4 + r) * 132 + g * 16 + m] = acc[g][r];
        __syncthreads();
#pragma unroll
        for (int it = 0; it < 8; it++) {  // 64 rows x 32 slots
            int idx = tid + it * 256;
            int row = idx >> 5, c4 = (idx & 31) * 4;
            int node = nperm[row0 + row];
            if (node < 0) continue;
            float4 v = *(const float4*)(Cb + row * 132 + c4);
            if (EPI == 1) {
                float4 bv = *(const float4*)(bias + t * 128 + c4);
                v.x += bv.x; v.y += bv.y; v.z += bv.z; v.w += bv.w;
                const float is2 = 0.70710678118654752f;
                v.x = 0.5f * v.x * (1.f + erff(v.x * is2));
                v.y = 0.5f * v.y * (1.f + erff(v.y * is2));
                v.z = 0.5f * v.z * (1.f + erff(v.z * is2));
                v.w = 0.5f * v.w * (1.f + erff(v.w * is2));
            }
            int col = cb * 128 + c4;
            if (OMODE == 0 || OMODE == 2)
                *(float4*)(Yf + (size_t)node * WIDTH + col) = v;
            if (OMODE == 1 || OMODE == 2) {
                uint2 pk;
                pk.x = f2bf(v.x) | (f2bf(v.y) << 16);
                pk.y = f2bf(v.z) | (f2bf(v.w) << 16);
                *(uint2*)(Yb + (size_t)node * WIDTH + col) = pk;
            }
        }
    }
}

// ---------------- fused edge pass (bf16 k/qhat/vhat; pri/sqrtD folded into qhat) -------
__global__ void k_edge(const unsigned short* __restrict__ kb,
                       const unsigned short* __restrict__ qhat,
                       const unsigned short* __restrict__ vhat,
                       const int* __restrict__ offs, const int* __restrict__ eidx,
                       const int* __restrict__ src, const int* __restrict__ etype,
                       unsigned short* __restrict__ aggb) {
    int lane = threadIdx.x & 63;
    int wid = blockIdx.x * (blockDim.x >> 6) + (threadIdx.x >> 6);
    int nw = gridDim.x * (blockDim.x >> 6);
    int h = lane >> 4;
    int i2 = (lane & 15) * 2;
    int hoff = h * 32 + i2;
    for (int n = wid; n < NN; n += nw) {
        int e0 = offs[n], e1 = offs[n + 1];
        float ax = 0.f, ay = 0.f, den = 0.f;
        const unsigned short* qrow = qhat + (size_t)n * 768;
        int e, s, t;
        if (e0 < e1) { e = eidx[e0]; s = src[e]; t = etype[e]; }
        for (int j = e0; j < e1; j++) {
            unsigned ku = *(const unsigned*)(kb + (size_t)s * 128 + hoff);
            int toff = (h * 6 + t) * 32 + i2;
            unsigned qu = *(const unsigned*)(qrow + toff);
            unsigned vu = *(const unsigned*)(vhat + (size_t)s * 768 + toff);
            if (j + 1 < e1) { e = eidx[j + 1]; s = src[e]; t = etype[e]; }  // prefetch
            float part = bf_lo(ku) * bf_lo(qu) + bf_hi(ku) * bf_hi(qu);
            part += __shfl_xor(part, 1);
            part += __shfl_xor(part, 2);
            part += __shfl_xor(part, 4);
            part += __shfl_xor(part, 8);
            float ex = __expf(part);
            den += ex;
            ax += ex * bf_lo(vu);
            ay += ex * bf_hi(vu);
        }
        float r = (den > 0.f) ? (1.0f / den) : 0.f;
        unsigned pk = f2bf(ax * r) | (f2bf(ay * r) << 16);
        *(unsigned*)(aggb + (size_t)n * 128 + hoff) = pk;
    }
}

// ---------------- skip-blend + LayerNorm; writes h fp32 + hb bf16 ----------------
__global__ void k_blend_ln(const float* __restrict__ ha, float* __restrict__ h,
                           unsigned short* __restrict__ hb, const int* __restrict__ ntype,
                           const float* __restrict__ skip, const float* __restrict__ gamma,
                           const float* __restrict__ beta) {
    int lane = threadIdx.x & 63;
    int w = threadIdx.x >> 6;
    int n = blockIdx.x * 4 + w;
    if (n >= NN) return;
    int off = lane * 2;
    int t = ntype[n];
    float alpha = 1.0f / (1.0f + __expf(-skip[t]));
    float2 a2 = *(const float2*)(ha + (size_t)n * 128 + off);
    float2 h2 = *(const float2*)(h + (size_t)n * 128 + off);
    float ox = a2.x * alpha + h2.x * (1.f - alpha);
    float oy = a2.y * alpha + h2.y * (1.f - alpha);
    float s = ox + oy;
#pragma unroll
    for (int m = 1; m < 64; m <<= 1) s += __shfl_xor(s, m);
    float mu = s * (1.0f / 128.0f);
    float dx = ox - mu, dy = oy - mu;
    float v = dx * dx + dy * dy;
#pragma unroll
    for (int m = 1; m < 64; m <<= 1) v += __shfl_xor(v, m);
    float rs = rsqrtf(v * (1.0f / 128.0f) + 1e-5f);
    float2 g2 = *(const float2*)(gamma + off);
    float2 b2 = *(const float2*)(beta + off);
    float vx = dx * rs * g2.x + b2.x;
    float vy = dy * rs * g2.y + b2.y;
    *(float2*)(h + (size_t)n * 128 + off) = make_float2(vx, vy);
    *(unsigned*)(hb + (size_t)n * 128 + off) = f2bf(vx) | (f2bf(vy) << 16);
}

// ---------------- output projection ----------------
__global__ void k_out(const float* __restrict__ h, const float* __restrict__ Wo,
                      const float* __restrict__ bo, float* __restrict__ out) {
    __shared__ float Ws[128 * 16];
    int tid = threadIdx.x;
#pragma unroll
    for (int it = 0; it < 2; it++) {
        int idx = (tid + it * 256) * 4;
        *(float4*)(&Ws[idx]) = *(const float4*)(Wo + idx);
    }
    __syncthreads();
    int nl = tid >> 4;
    int o = tid & 15;
    int n = blockIdx.x * 16 + nl;
    float acc = bo[o];
    const float* hr = h + (size_t)n * 128;
#pragma unroll
    for (int kk = 0; kk < 128; kk += 4) {
        float4 hv = *(const float4*)(hr + kk);
        acc += hv.x * Ws[kk * 16 + o] + hv.y * Ws[(kk + 1) * 16 + o] +
               hv.z * Ws[(kk + 2) * 16 + o] + hv.w * Ws[(kk + 3) * 16 + o];
    }
    out[(size_t)n * 16 + o] = acc;
}

extern "C" void kernel_launch(void* const* d_in, const int* in_sizes, int n_in,
                              void* d_out, int out_size, void* d_ws, size_t ws_size,
                              hipStream_t stream) {
    const float* x       = (const float*)d_in[0];
    const float* adapt_W = (const float*)d_in[1];
    const float* adapt_b = (const float*)d_in[2];
    const float* Wk      = (const float*)d_in[3];
    const float* Wq      = (const float*)d_in[4];
    const float* Wv      = (const float*)d_in[5];
    const float* pri     = (const float*)d_in[6];
    const float* Wa      = (const float*)d_in[7];
    const float* Wm      = (const float*)d_in[8];
    const float* Wla     = (const float*)d_in[9];
    const float* skip    = (const float*)d_in[10];
    const float* gamma   = (const float*)d_in[11];
    const float* beta    = (const float*)d_in[12];
    const float* out_W   = (const float*)d_in[13];
    const float* out_b   = (const float*)d_in[14];
    const int* ntype     = (const int*)d_in[15];
    const int* etype     = (const int*)d_in[16];
    const int* src       = (const int*)d_in[17];
    const int* dst       = (const int*)d_in[18];
    float* out = (float*)d_out;

    char* p = (char*)d_ws;
    auto al = [](size_t v) { return (v + 255) & ~(size_t)255; };
    float* h  = (float*)p;          p += al((size_t)NN * 128 * 4);
    float* ha = (float*)p;          p += al((size_t)NN * 128 * 4);
    // xb (bf16 input copy) aliases ha: xb dead after adapt GEMM, ha first
    // written by layer-0 Wla GEMM
    unsigned short* xb = (unsigned short*)ha;
    unsigned short* hb   = (unsigned short*)p; p += al((size_t)NN * 128 * 2);
    unsigned short* kb   = (unsigned short*)p; p += al((size_t)NN * 128 * 2);
    unsigned short* aggb = (unsigned short*)p; p += al((size_t)NN * 128 * 2);
    unsigned short* qhat = (unsigned short*)p; p += al((size_t)NN * 768 * 2);
    unsigned short* vhat = (unsigned short*)p; p += al((size_t)NN * 768 * 2);
    unsigned short* adaptT = (unsigned short*)p; p += al((size_t)TNN * 128 * 256 * 2);
    unsigned short* WkT    = (unsigned short*)p; p += al((size_t)LLL * TNN * 16384 * 2);
    unsigned short* WlaT   = (unsigned short*)p; p += al((size_t)LLL * TNN * 16384 * 2);
    unsigned short* combQ  = (unsigned short*)p; p += al((size_t)LLL * TNN * 768 * 128 * 2);
    unsigned short* combV  = (unsigned short*)p; p += al((size_t)LLL * TNN * 768 * 128 * 2);
    int* deg   = (int*)p; p += al((size_t)NN * 4);
    int* offs  = (int*)p; p += al((size_t)(NN + 1) * 4);
    int* cur   = (int*)p; p += al((size_t)NN * 4);
    int* eidx  = (int*)p; p += al((size_t)EE * 4);
    int* nperm = (int*)p; p += al((size_t)(NN + 512) * 4);
    int* ncnt  = (int*)p; p += al(64);
    int* ncur  = (int*)p; p += al(64);
    int* meta  = (int*)p; p += al(64);

    k_init<<<(NN + 512 + 255) / 256, 256, 0, stream>>>(deg, cur, ncnt, ncur, nperm);
    k_count_edges<<<(EE + 255) / 256, 256, 0, stream>>>(dst, deg);
    k_count_types<<<(NN + 255) / 256, 256, 0, stream>>>(ntype, ncnt);
    k_scan<<<1, 1024, 0, stream>>>(deg, offs, ncnt, meta);
    k_scatter_edges<<<(EE + 255) / 256, 256, 0, stream>>>(dst, offs, cur, eidx);
    k_scatter_nodes<<<(NN + 255) / 256, 256, 0, stream>>>(ntype, meta, ncur, nperm);

    k_cvt_x<<<(NN * 256 / 8 + 255) / 256, 256, 0, stream>>>(x, xb);
    k_wt<<<96, 256, 0, stream>>>(adapt_W, Wk, Wla, adaptT, WkT, WlaT);
    k_comb<<<384, 256, 0, stream>>>(Wq, Wa, Wv, Wm, pri, combQ, combV);

    const int TILES = NN / 64 + TNN + 1;

    // adapt: h = gelu(xb @ adaptT + b), also hb bf16
    k_gemm<256, 1, 1, 2><<<TILES, 256, 0, stream>>>(xb, adaptT, adapt_b, h, hb, nperm, meta);

    for (int l = 0; l < LLL; l++) {
        k_gemm<128, 1, 0, 1><<<TILES, 256, 0, stream>>>(
            hb, WkT + (size_t)l * TNN * 16384, nullptr, nullptr, kb, nperm, meta);
        k_gemm<128, 6, 0, 1><<<TILES, 256, 0, stream>>>(
            hb, combQ + (size_t)l * TNN * 768 * 128, nullptr, nullptr, qhat, nperm, meta);
        k_gemm<128, 6, 0, 1><<<TILES, 256, 0, stream>>>(
            hb, combV + (size_t)l * TNN * 768 * 128, nullptr, nullptr, vhat, nperm, meta);

        k_edge<<<4096, 256, 0, stream>>>(kb, qhat, vhat, offs, eidx, src, etype, aggb);

        k_gemm<128, 1, 0, 0><<<TILES, 256, 0, stream>>>(
            aggb, WlaT + (size_t)l * TNN * 16384, nullptr, ha, nullptr, nperm, meta);
        k_blend_ln<<<(NN + 3) / 4, 256, 0, stream>>>(ha, h, hb, ntype, skip + (size_t)l * TNN,
                                                     gamma + (size_t)l * HIDD,
                                                     beta + (size_t)l * HIDD);
    }

    k_out<<<NN / 16, 256, 0, stream>>>(h, out_W, out_b, out);
}

// Round 8
// 668.193 us; speedup vs baseline: 9.4929x; 1.1948x over previous
//
#include <hip/hip_runtime.h>
#include <hip/hip_bf16.h>
#include <math.h>

#define NN   50000
#define EE   400000
#define NINP 256
#define HH   4
#define DD   32
#define HIDD 128
#define TNN  4
#define TEE  6
#define LLL  2
#define NOUTT 16
#define NB   196   // (NN+255)/256 scan blocks

// RULE: every LDS array row stride must be a multiple of 4 fp32 / 8 bf16
// elements so vector b128 accesses stay 16B-aligned (2 crashed rounds).
// RULE: every LDS staging loop must cover rows*cols/threads slots (round 6).

typedef __attribute__((ext_vector_type(8))) short bf16x8;
typedef __attribute__((ext_vector_type(4))) float f32x4;

__device__ __forceinline__ float bf_lo(unsigned u) { return __uint_as_float(u << 16); }
__device__ __forceinline__ float bf_hi(unsigned u) { return __uint_as_float(u & 0xFFFF0000u); }
__device__ __forceinline__ unsigned f2bf(float f) {
    unsigned u = __float_as_uint(f);
    u += 0x7FFFu + ((u >> 16) & 1u);
    return (u >> 16);
}

// ---------------- workspace init ----------------
__global__ void k_init(int* __restrict__ deg, int* __restrict__ cur, int* __restrict__ ncnt,
                       int* __restrict__ ncur, int* __restrict__ nperm) {
    int i = blockIdx.x * 256 + threadIdx.x;
    if (i < NN) { deg[i] = 0; cur[i] = 0; }
    if (i < 16) { ncnt[i] = 0; ncur[i] = 0; }
    if (i < NN + 512) nperm[i] = -1;
}

// ---------------- CSR / sort build ----------------
__global__ void k_count_edges(const int* __restrict__ dst, int* __restrict__ deg) {
    int e = blockIdx.x * 256 + threadIdx.x;
    if (e < EE) atomicAdd(&deg[dst[e]], 1);
}
__global__ void k_count_types(const int* __restrict__ ntype, int* __restrict__ ncnt) {
    int n = blockIdx.x * 256 + threadIdx.x;
    int lane = threadIdx.x & 63;
    int t = (n < NN) ? ntype[n] : -1;
#pragma unroll
    for (int tt = 0; tt < TNN; tt++) {
        unsigned long long mask = __ballot(t == tt);
        if (mask && lane == (__ffsll((unsigned long long)mask) - 1))
            atomicAdd(&ncnt[tt], __popcll(mask));
    }
}
// 3-pass scan (replaces 49-iteration single-block ladder)
__global__ void k_scan1(const int* __restrict__ deg, int* __restrict__ bsum) {
    int i = blockIdx.x * 256 + threadIdx.x;
    int lane = threadIdx.x & 63, wv = threadIdx.x >> 6;
    __shared__ int ws[4];
    int x = (i < NN) ? deg[i] : 0;
#pragma unroll
    for (int off = 1; off < 64; off <<= 1) x += __shfl_xor(x, off);
    if (lane == 0) ws[wv] = x;
    __syncthreads();
    if (threadIdx.x == 0) bsum[blockIdx.x] = ws[0] + ws[1] + ws[2] + ws[3];
}
__global__ void k_scan2(const int* __restrict__ bsum, int* __restrict__ bpre,
                        const int* __restrict__ ncnt, int* __restrict__ meta) {
    __shared__ int ws[4];
    int tid = threadIdx.x, lane = tid & 63, wv = tid >> 6;
    int v = (tid < NB) ? bsum[tid] : 0;
    int x = v;
#pragma unroll
    for (int off = 1; off < 64; off <<= 1) {
        int y = __shfl_up(x, off);
        if (lane >= off) x += y;
    }
    if (lane == 63) ws[wv] = x;
    __syncthreads();
    if (tid == 0) { int a = 0; for (int w = 0; w < 4; w++) { int s = ws[w]; ws[w] = a; a += s; } }
    __syncthreads();
    if (tid < NB) bpre[tid] = x - v + ws[wv];
    if (tid == 0) {
        int acc = 0;
        meta[0] = 0;
        for (int t = 0; t < TNN; t++) { acc += ((ncnt[t] + 63) >> 6) << 6; meta[t + 1] = acc; }
    }
}
__global__ void k_scan3(const int* __restrict__ deg, const int* __restrict__ bpre,
                        int* __restrict__ offs) {
    int b = blockIdx.x;
    int tid = threadIdx.x, lane = tid & 63, wv = tid >> 6;
    int i = b * 256 + tid;
    __shared__ int ws[4];
    int v = (i < NN) ? deg[i] : 0;
    int x = v;
#pragma unroll
    for (int off = 1; off < 64; off <<= 1) {
        int y = __shfl_up(x, off);
        if (lane >= off) x += y;
    }
    if (lane == 63) ws[wv] = x;
    __syncthreads();
    if (tid == 0) { int a = 0; for (int w = 0; w < 4; w++) { int s = ws[w]; ws[w] = a; a += s; } }
    __syncthreads();
    if (i < NN) offs[i + 1] = x + ws[wv] + bpre[b];
    if (b == 0 && tid == 0) offs[0] = 0;
}
__global__ void k_scatter_edges(const int* __restrict__ dst, const int* __restrict__ offs,
                                int* __restrict__ cur, int* __restrict__ eidx) {
    int e = blockIdx.x * 256 + threadIdx.x;
    if (e < EE) {
        int d = dst[e];
        int p = atomicAdd(&cur[d], 1);
        eidx[offs[d] + p] = e;
    }
}
__global__ void k_scatter_nodes(const int* __restrict__ ntype, const int* __restrict__ meta,
                                int* __restrict__ ncur, int* __restrict__ nperm) {
    int n = blockIdx.x * 256 + threadIdx.x;
    int lane = threadIdx.x & 63;
    int t = (n < NN) ? ntype[n] : -1;
#pragma unroll
    for (int tt = 0; tt < TNN; tt++) {
        unsigned long long mask = __ballot(t == tt);
        if (t == tt) {
            int rank = __popcll(mask & ((1ull << lane) - 1ull));
            int leader = __ffsll((unsigned long long)mask) - 1;
            int b = 0;
            if (rank == 0) b = atomicAdd(&ncur[tt], __popcll(mask));
            b = __shfl(b, leader);
            nperm[meta[tt] + b + rank] = n;
        }
    }
}

// ---------------- x -> bf16 ----------------
__global__ void k_cvt_x(const float* __restrict__ x, unsigned short* __restrict__ xb) {
    size_t i = ((size_t)blockIdx.x * 256 + threadIdx.x) * 8;
    float4 a = *(const float4*)(x + i);
    float4 b = *(const float4*)(x + i + 4);
    uint4 pk;
    pk.x = f2bf(a.x) | (f2bf(a.y) << 16);
    pk.y = f2bf(a.z) | (f2bf(a.w) << 16);
    pk.z = f2bf(b.x) | (f2bf(b.y) << 16);
    pk.w = f2bf(b.z) | (f2bf(b.w) << 16);
    *(uint4*)(xb + i) = pk;
}

// ---------------- weight transpose+convert: W[t][k][n] f32 -> WT[t][n][k] bf16 ----------
// blocks 0..31 adapt (K=256) -> adaptT; 32..63 Wk -> Wf rows 0..127; 64..95 Wla -> WlaT
__global__ void k_wt(const float* __restrict__ adapt_W, const float* __restrict__ Wk,
                     const float* __restrict__ Wla, unsigned short* __restrict__ adaptT,
                     unsigned short* __restrict__ Wf, unsigned short* __restrict__ WlaT) {
    __shared__ float Ts[64][68];  // 272B row stride, 16B multiple
    int b = blockIdx.x, tid = threadIdx.x;
    const float* src;
    unsigned short* dst;
    int K, kt, nt;
    if (b < 32) {
        int t = b >> 3, tile = b & 7;
        K = 256; kt = tile >> 1; nt = tile & 1;
        src = adapt_W + (size_t)t * 256 * 128;
        dst = adaptT + (size_t)t * 128 * 256;
    } else if (b < 64) {
        int b2 = b - 32, l = b2 >> 4, r = b2 & 15, t = r >> 2, tile = r & 3;
        K = 128; kt = tile >> 1; nt = tile & 1;
        src = Wk + (size_t)(l * 4 + t) * 16384;
        dst = Wf + (size_t)(l * TNN + t) * 1664 * 128;  // fused rows 0..127
    } else {
        int b2 = b - 64, l = b2 >> 4, r = b2 & 15, t = r >> 2, tile = r & 3;
        K = 128; kt = tile >> 1; nt = tile & 1;
        src = Wla + (size_t)(l * 4 + t) * 16384;
        dst = WlaT + (size_t)(l * 4 + t) * 16384;
    }
    int k0 = kt * 64, n0 = nt * 64;
#pragma unroll
    for (int it = 0; it < 4; it++) {  // 64 rows x 16 slots = 1024 = 256*4
        int idx = tid + it * 256;
        int row = idx >> 4, c4 = (idx & 15) * 4;
        *(float4*)(&Ts[row][c4]) = *(const float4*)(src + (size_t)(k0 + row) * 128 + n0 + c4);
    }
    __syncthreads();
#pragma unroll
    for (int it = 0; it < 2; it++) {  // 64 rows x 8 slots = 512 = 256*2
        int idx = tid + it * 256;
        int nn = idx >> 3, sg = (idx & 7) * 8;
        uint4 pk;
        pk.x = f2bf(Ts[sg + 0][nn]) | (f2bf(Ts[sg + 1][nn]) << 16);
        pk.y = f2bf(Ts[sg + 2][nn]) | (f2bf(Ts[sg + 3][nn]) << 16);
        pk.z = f2bf(Ts[sg + 4][nn]) | (f2bf(Ts[sg + 5][nn]) << 16);
        pk.w = f2bf(Ts[sg + 6][nn]) | (f2bf(Ts[sg + 7][nn]) << 16);
        *(uint4*)(dst + (size_t)(n0 + nn) * K + k0 + sg) = pk;
    }
}

// ---------------- combined weights into fused buffer ----------------
// Wf[l][t] rows 128..895  = combQ[j=(h,te,d)][k] = sum_o Wq[k][h*32+o]*Wa[h][te][d][o]*pri/sqrtD
// Wf[l][t] rows 896..1663 = combV[j=(h,te,o)][k] = sum_d Wv[k][h*32+d]*Wm[h][te][d][o]
__global__ void k_comb(const float* __restrict__ Wq, const float* __restrict__ Wa,
                       const float* __restrict__ Wv, const float* __restrict__ Wm,
                       const float* __restrict__ pri, unsigned short* __restrict__ Wf) {
    __shared__ float Ls[128][36];  // stride 36: 16B-aligned float4 rows
    __shared__ float Ss[32][36];
    __shared__ unsigned short Ot[32][136];
    int b = blockIdx.x, tid = threadIdx.x;
    int mode = b / 192;
    int rem = b % 192;
    int l = rem / 96;
    int rem2 = rem % 96;
    int t = rem2 / 24;
    int ht = rem2 % 24;
    int hh = ht / 6, te = ht % 6;
    const float* L = (mode == 0 ? Wq : Wv) + ((size_t)(l * TNN + t)) * 16384;
    const float* S = (mode == 0 ? Wa : Wm) + ((size_t)((l * HH + hh) * TEE + te)) * 1024;
    float ps = (mode == 0) ? pri[(l * HH + hh) * TEE + te] * 0.17677669529663687f : 1.0f;
#pragma unroll
    for (int it = 0; it < 4; it++) {  // 128 rows x 8 slots = 1024 = 256*4
        int idx = tid + it * 256;
        int kk = idx >> 3, c4 = (idx & 7) * 4;
        *(float4*)(&Ls[kk][c4]) = *(const float4*)(L + (size_t)kk * 128 + hh * 32 + c4);
    }
    {
        int r = tid >> 3, c4 = (tid & 7) * 4;  // 32 x 8 = 256
        *(float4*)(&Ss[r][c4]) = *(const float4*)(S + r * 32 + c4);
    }
    __syncthreads();
    int k = tid >> 1, half = tid & 1;
#pragma unroll
    for (int jj = 0; jj < 16; jj++) {
        int j = half * 16 + jj;
        float s = 0.f;
        if (mode == 0) {
#pragma unroll
            for (int o = 0; o < 32; o++) s += Ls[k][o] * Ss[j][o];
        } else {
#pragma unroll
            for (int d = 0; d < 32; d++) s += Ls[k][d] * Ss[d][j];
        }
        Ot[j][k] = (unsigned short)f2bf(s * ps);
    }
    __syncthreads();
    unsigned short* dst = Wf + ((size_t)(l * TNN + t) * 1664 + (mode == 0 ? 128 : 896)) * 128;
#pragma unroll
    for (int it = 0; it < 2; it++) {  // 32 rows x 16 slots = 512 = 256*2
        int idx = tid + it * 256;
        int j = idx >> 4, sg = (idx & 15) * 8;
        uint4 pk = *(const uint4*)(&Ot[j][sg]);
        int jg = (hh * 6 + te) * 32 + j;
        *(uint4*)(dst + (size_t)jg * 128 + sg) = pk;
    }
}

// ---------------- MFMA typed GEMM ----------------
// Y[node] = A[node] @ WT[type]^T ; A bf16 [node][K], WT bf16 [t][NCB*128][K]
// EPI: 1 = +bias, exact gelu. OMODE: 0 fp32 out, 1 bf16 out, 2 both
template <int K, int NCB, int EPI, int OMODE>
__launch_bounds__(256) __global__
void k_gemm(const unsigned short* __restrict__ A, const unsigned short* __restrict__ WT,
            const float* __restrict__ bias, float* __restrict__ Yf,
            unsigned short* __restrict__ Yb, const int* __restrict__ nperm,
            const int* __restrict__ meta) {
    __shared__ __align__(16) char smem[52224];
    unsigned short* Ab = (unsigned short*)smem;            // [64][136] bf16 (272B stride)
    unsigned short* Bs = (unsigned short*)(smem + 17408);  // [128][136] bf16
    float* Cb = (float*)(smem + 17408);                    // [64][132] f32 (alias Bs)
    const int WIDTH = NCB * 128;
    int row0 = blockIdx.x * 64;
    if (row0 >= meta[4]) return;
    int t = 0;
    while (t < 3 && row0 >= meta[t + 1]) t++;
    const unsigned short* WTt = WT + (size_t)t * WIDTH * K;
    int tid = threadIdx.x;
    int lane = tid & 63, w = tid >> 6;
    int m = lane & 15, q = lane >> 4;

#pragma unroll 1
    for (int cb = 0; cb < NCB; cb++) {
        f32x4 acc[8];
#pragma unroll
        for (int g = 0; g < 8; g++) acc[g] = (f32x4){0.f, 0.f, 0.f, 0.f};
#pragma unroll
        for (int kc = 0; kc < K / 128; kc++) {
            __syncthreads();  // prior epilogue reads of Cb(=Bs) done
            if (NCB == 1 || cb == 0) {
#pragma unroll
                for (int it = 0; it < 4; it++) {  // 64 rows x 16 slots
                    int idx = tid + it * 256;
                    int r = idx >> 4, sg = idx & 15;
                    int node = nperm[row0 + r];
                    uint4 v = make_uint4(0, 0, 0, 0);
                    if (node >= 0) v = *(const uint4*)(A + (size_t)node * K + kc * 128 + sg * 8);
                    *(uint4*)(Ab + r * 136 + sg * 8) = v;
                }
            }
#pragma unroll
            for (int it = 0; it < 8; it++) {  // 128 rows x 16 slots
                int idx = tid + it * 256;
                int n = idx >> 4, sg = idx & 15;
                *(uint4*)(Bs + n * 136 + sg * 8) =
                    *(const uint4*)(WTt + (size_t)(cb * 128 + n) * K + kc * 128 + sg * 8);
            }
            __syncthreads();
#pragma unroll
            for (int k0 = 0; k0 < 128; k0 += 32) {
                bf16x8 a = *(const bf16x8*)(Ab + (w * 16 + m) * 136 + k0 + q * 8);
#pragma unroll
                for (int g = 0; g < 8; g++) {
                    bf16x8 bb = *(const bf16x8*)(Bs + (g * 16 + m) * 136 + k0 + q * 8);
                    acc[g] = __builtin_amdgcn_mfma_f32_16x16x32_bf16(a, bb, acc[g], 0, 0, 0);
                }
            }
        }
        __syncthreads();  // mfma LDS reads done before Cb (alias Bs) write
#pragma unroll
        for (int g = 0; g < 8; g++)
#pragma unroll
            for (int r = 0; r < 4; r++)
                Cb[(w * 16 + q * 4 + r) * 132 + g * 16 + m] = acc[g][r];
        __syncthreads();
#pragma unroll
        for (int it = 0; it < 8; it++) {  // 64 rows x 32 slots
            int idx = tid + it * 256;
            int row = idx >> 5, c4 = (idx & 31) * 4;
            int node = nperm[row0 + row];
            if (node < 0) continue;
            float4 v = *(const float4*)(Cb + row * 132 + c4);
            if (EPI == 1) {
                float4 bv = *(const float4*)(bias + t * 128 + c4);
                v.x += bv.x; v.y += bv.y; v.z += bv.z; v.w += bv.w;
                const float is2 = 0.70710678118654752f;
                v.x = 0.5f * v.x * (1.f + erff(v.x * is2));
                v.y = 0.5f * v.y * (1.f + erff(v.y * is2));
                v.z = 0.5f * v.z * (1.f + erff(v.z * is2));
                v.w = 0.5f * v.w * (1.f + erff(v.w * is2));
            }
            int col = cb * 128 + c4;
            if (OMODE == 0 || OMODE == 2)
                *(float4*)(Yf + (size_t)node * WIDTH + col) = v;
            if (OMODE == 1 || OMODE == 2) {
                uint2 pk;
                pk.x = f2bf(v.x) | (f2bf(v.y) << 16);
                pk.y = f2bf(v.z) | (f2bf(v.w) << 16);
                *(uint2*)(Yb + (size_t)node * WIDTH + col) = pk;
            }
        }
    }
}

// ---------------- fused edge pass, 2-edge unrolled ----------------
// kqv[n][1664]: cols 0..127 = k, 128..895 = qhat, 896..1663 = vhat
__global__ void k_edge(const unsigned short* __restrict__ kqv,
                       const int* __restrict__ offs, const int* __restrict__ eidx,
                       const int* __restrict__ src, const int* __restrict__ etype,
                       unsigned short* __restrict__ aggb) {
    int lane = threadIdx.x & 63;
    int wid = blockIdx.x * (blockDim.x >> 6) + (threadIdx.x >> 6);
    int nw = gridDim.x * (blockDim.x >> 6);
    int h = lane >> 4;
    int i2 = (lane & 15) * 2;
    int hoff = h * 32 + i2;
    for (int n = wid; n < NN; n += nw) {
        int e0 = offs[n], e1 = offs[n + 1];
        float ax = 0.f, ay = 0.f, den = 0.f;
        const unsigned short* qrow = kqv + (size_t)n * 1664 + 128;
        int sA = 0, tA = 0, sB = 0, tB = 0;
        if (e0 < e1) { int e = eidx[e0]; sA = src[e]; tA = etype[e]; }
        if (e0 + 1 < e1) { int e = eidx[e0 + 1]; sB = src[e]; tB = etype[e]; }
        int j = e0;
        while (j + 1 < e1) {
            int toA = (h * 6 + tA) * 32 + i2;
            int toB = (h * 6 + tB) * 32 + i2;
            unsigned kuA = *(const unsigned*)(kqv + (size_t)sA * 1664 + hoff);
            unsigned quA = *(const unsigned*)(qrow + toA);
            unsigned vuA = *(const unsigned*)(kqv + (size_t)sA * 1664 + 896 + toA);
            unsigned kuB = *(const unsigned*)(kqv + (size_t)sB * 1664 + hoff);
            unsigned quB = *(const unsigned*)(qrow + toB);
            unsigned vuB = *(const unsigned*)(kqv + (size_t)sB * 1664 + 896 + toB);
            int jn = j + 2;
            if (jn < e1) { int e = eidx[jn]; sA = src[e]; tA = etype[e]; }
            if (jn + 1 < e1) { int e = eidx[jn + 1]; sB = src[e]; tB = etype[e]; }
            float pA = bf_lo(kuA) * bf_lo(quA) + bf_hi(kuA) * bf_hi(quA);
            float pB = bf_lo(kuB) * bf_lo(quB) + bf_hi(kuB) * bf_hi(quB);
            pA += __shfl_xor(pA, 1); pB += __shfl_xor(pB, 1);
            pA += __shfl_xor(pA, 2); pB += __shfl_xor(pB, 2);
            pA += __shfl_xor(pA, 4); pB += __shfl_xor(pB, 4);
            pA += __shfl_xor(pA, 8); pB += __shfl_xor(pB, 8);
            float exA = __expf(pA), exB = __expf(pB);
            den += exA + exB;
            ax += exA * bf_lo(vuA) + exB * bf_lo(vuB);
            ay += exA * bf_hi(vuA) + exB * bf_hi(vuB);
            j = jn;
        }
        if (j < e1) {  // odd leftover: sA/tA hold the last edge
            int toA = (h * 6 + tA) * 32 + i2;
            unsigned kuA = *(const unsigned*)(kqv + (size_t)sA * 1664 + hoff);
            unsigned quA = *(const unsigned*)(qrow + toA);
            unsigned vuA = *(const unsigned*)(kqv + (size_t)sA * 1664 + 896 + toA);
            float pA = bf_lo(kuA) * bf_lo(quA) + bf_hi(kuA) * bf_hi(quA);
            pA += __shfl_xor(pA, 1);
            pA += __shfl_xor(pA, 2);
            pA += __shfl_xor(pA, 4);
            pA += __shfl_xor(pA, 8);
            float exA = __expf(pA);
            den += exA;
            ax += exA * bf_lo(vuA);
            ay += exA * bf_hi(vuA);
        }
        float r = (den > 0.f) ? (1.0f / den) : 0.f;
        unsigned pk = f2bf(ax * r) | (f2bf(ay * r) << 16);
        *(unsigned*)(aggb + (size_t)n * 128 + hoff) = pk;
    }
}

// ---------------- skip-blend + LayerNorm; writes h fp32 + hb bf16 ----------------
__global__ void k_blend_ln(const float* __restrict__ ha, float* __restrict__ h,
                           unsigned short* __restrict__ hb, const int* __restrict__ ntype,
                           const float* __restrict__ skip, const float* __restrict__ gamma,
                           const float* __restrict__ beta) {
    int lane = threadIdx.x & 63;
    int w = threadIdx.x >> 6;
    int n = blockIdx.x * 4 + w;
    if (n >= NN) return;
    int off = lane * 2;
    int t = ntype[n];
    float alpha = 1.0f / (1.0f + __expf(-skip[t]));
    float2 a2 = *(const float2*)(ha + (size_t)n * 128 + off);
    float2 h2 = *(const float2*)(h + (size_t)n * 128 + off);
    float ox = a2.x * alpha + h2.x * (1.f - alpha);
    float oy = a2.y * alpha + h2.y * (1.f - alpha);
    float s = ox + oy;
#pragma unroll
    for (int m = 1; m < 64; m <<= 1) s += __shfl_xor(s, m);
    float mu = s * (1.0f / 128.0f);
    float dx = ox - mu, dy = oy - mu;
    float v = dx * dx + dy * dy;
#pragma unroll
    for (int m = 1; m < 64; m <<= 1) v += __shfl_xor(v, m);
    float rs = rsqrtf(v * (1.0f / 128.0f) + 1e-5f);
    float2 g2 = *(const float2*)(gamma + off);
    float2 b2 = *(const float2*)(beta + off);
    float vx = dx * rs * g2.x + b2.x;
    float vy = dy * rs * g2.y + b2.y;
    *(float2*)(h + (size_t)n * 128 + off) = make_float2(vx, vy);
    *(unsigned*)(hb + (size_t)n * 128 + off) = f2bf(vx) | (f2bf(vy) << 16);
}

// ---------------- output projection ----------------
__global__ void k_out(const float* __restrict__ h, const float* __restrict__ Wo,
                      const float* __restrict__ bo, float* __restrict__ out) {
    __shared__ float Ws[128 * 16];
    int tid = threadIdx.x;
#pragma unroll
    for (int it = 0; it < 2; it++) {
        int idx = (tid + it * 256) * 4;
        *(float4*)(&Ws[idx]) = *(const float4*)(Wo + idx);
    }
    __syncthreads();
    int nl = tid >> 4;
    int o = tid & 15;
    int n = blockIdx.x * 16 + nl;
    float acc = bo[o];
    const float* hr = h + (size_t)n * 128;
#pragma unroll
    for (int kk = 0; kk < 128; kk += 4) {
        float4 hv = *(const float4*)(hr + kk);
        acc += hv.x * Ws[kk * 16 + o] + hv.y * Ws[(kk + 1) * 16 + o] +
               hv.z * Ws[(kk + 2) * 16 + o] + hv.w * Ws[(kk + 3) * 16 + o];
    }
    out[(size_t)n * 16 + o] = acc;
}

extern "C" void kernel_launch(void* const* d_in, const int* in_sizes, int n_in,
                              void* d_out, int out_size, void* d_ws, size_t ws_size,
                              hipStream_t stream) {
    const float* x       = (const float*)d_in[0];
    const float* adapt_W = (const float*)d_in[1];
    const float* adapt_b = (const float*)d_in[2];
    const float* Wk      = (const float*)d_in[3];
    const float* Wq      = (const float*)d_in[4];
    const float* Wv      = (const float*)d_in[5];
    const float* pri     = (const float*)d_in[6];
    const float* Wa      = (const float*)d_in[7];
    const float* Wm      = (const float*)d_in[8];
    const float* Wla     = (const float*)d_in[9];
    const float* skip    = (const float*)d_in[10];
    const float* gamma   = (const float*)d_in[11];
    const float* beta    = (const float*)d_in[12];
    const float* out_W   = (const float*)d_in[13];
    const float* out_b   = (const float*)d_in[14];
    const int* ntype     = (const int*)d_in[15];
    const int* etype     = (const int*)d_in[16];
    const int* src       = (const int*)d_in[17];
    const int* dst       = (const int*)d_in[18];
    float* out = (float*)d_out;

    char* p = (char*)d_ws;
    auto al = [](size_t v) { return (v + 255) & ~(size_t)255; };
    float* h  = (float*)p;          p += al((size_t)NN * 128 * 4);
    float* ha = (float*)p;          p += al((size_t)NN * 128 * 4);
    // xb aliases ha (xb dead after adapt GEMM; ha first written by Wla GEMM)
    unsigned short* xb = (unsigned short*)ha;
    unsigned short* hb   = (unsigned short*)p; p += al((size_t)NN * 128 * 2);
    unsigned short* aggb = (unsigned short*)p; p += al((size_t)NN * 128 * 2);
    unsigned short* kqvb = (unsigned short*)p; p += al((size_t)NN * 1664 * 2);
    unsigned short* adaptT = (unsigned short*)p; p += al((size_t)TNN * 128 * 256 * 2);
    unsigned short* WlaT   = (unsigned short*)p; p += al((size_t)LLL * TNN * 16384 * 2);
    unsigned short* Wf     = (unsigned short*)p; p += al((size_t)LLL * TNN * 1664 * 128 * 2);
    int* deg   = (int*)p; p += al((size_t)NN * 4);
    int* offs  = (int*)p; p += al((size_t)(NN + 1) * 4);
    int* cur   = (int*)p; p += al((size_t)NN * 4);
    int* eidx  = (int*)p; p += al((size_t)EE * 4);
    int* nperm = (int*)p; p += al((size_t)(NN + 512) * 4);
    int* bsum  = (int*)p; p += al(256 * 4);
    int* bpre  = (int*)p; p += al(256 * 4);
    int* ncnt  = (int*)p; p += al(64);
    int* ncur  = (int*)p; p += al(64);
    int* meta  = (int*)p; p += al(64);

    k_init<<<(NN + 512 + 255) / 256, 256, 0, stream>>>(deg, cur, ncnt, ncur, nperm);
    k_count_edges<<<(EE + 255) / 256, 256, 0, stream>>>(dst, deg);
    k_count_types<<<(NN + 255) / 256, 256, 0, stream>>>(ntype, ncnt);
    k_scan1<<<NB, 256, 0, stream>>>(deg, bsum);
    k_scan2<<<1, 256, 0, stream>>>(bsum, bpre, ncnt, meta);
    k_scan3<<<NB, 256, 0, stream>>>(deg, bpre, offs);
    k_scatter_edges<<<(EE + 255) / 256, 256, 0, stream>>>(dst, offs, cur, eidx);
    k_scatter_nodes<<<(NN + 255) / 256, 256, 0, stream>>>(ntype, meta, ncur, nperm);

    k_cvt_x<<<(NN * 256 / 8 + 255) / 256, 256, 0, stream>>>(x, xb);
    k_wt<<<96, 256, 0, stream>>>(adapt_W, Wk, Wla, adaptT, Wf, WlaT);
    k_comb<<<384, 256, 0, stream>>>(Wq, Wa, Wv, Wm, pri, Wf);

    const int TILES = NN / 64 + TNN + 1;

    // adapt: h = gelu(xb @ adaptT + b), also hb bf16
    k_gemm<256, 1, 1, 2><<<TILES, 256, 0, stream>>>(xb, adaptT, adapt_b, h, hb, nperm, meta);

    for (int l = 0; l < LLL; l++) {
        // fused K|Q|V: kqv[n][1664] in one MFMA GEMM
        k_gemm<128, 13, 0, 1><<<TILES, 256, 0, stream>>>(
            hb, Wf + (size_t)l * TNN * 1664 * 128, nullptr, nullptr, kqvb, nperm, meta);

        k_edge<<<4096, 256, 0, stream>>>(kqvb, offs, eidx, src, etype, aggb);

        k_gemm<128, 1, 0, 0><<<TILES, 256, 0, stream>>>(
            aggb, WlaT + (size_t)l * TNN * 16384, nullptr, ha, nullptr, nperm, meta);
        k_blend_ln<<<(NN + 3) / 4, 256, 0, stream>>>(ha, h, hb, ntype, skip + (size_t)l * TNN,
                                                     gamma + (size_t)l * HIDD,
                                                     beta + (size_t)l * HIDD);
    }

    k_out<<<NN / 16, 256, 0, stream>>>(h, out_W, out_b, out);
}